// Round 14
// baseline (327.542 us; speedup 1.0000x reference)
//
#include <hip/hip_runtime.h>

#define HIMG 192
#define HWSZ (192*192)
#define NWX  24

typedef __bf16 bf16;
typedef __bf16 bf16x2 __attribute__((ext_vector_type(2)));
typedef __bf16 bf16x4 __attribute__((ext_vector_type(4)));
typedef __bf16 bf16x8 __attribute__((ext_vector_type(8)));
typedef float  f32x4  __attribute__((ext_vector_type(4)));

#define MFMA(a,b,c) __builtin_amdgcn_mfma_f32_16x16x32_bf16((a),(b),(c),0,0,0)
#define SW(r) (((((r)&7) ^ ((((r)>>3)&1)<<2))) << 4)

static __device__ __forceinline__ bf16x8 ldg8(const float* p) {
    const float4 u = ((const float4*)p)[0];
    const float4 v = ((const float4*)p)[1];
    bf16x8 r;
    r[0]=(bf16)u.x; r[1]=(bf16)u.y; r[2]=(bf16)u.z; r[3]=(bf16)u.w;
    r[4]=(bf16)v.x; r[5]=(bf16)v.y; r[6]=(bf16)v.z; r[7]=(bf16)v.w;
    return r;
}
template<int WSB>
static __device__ __forceinline__ bf16x8 ldw(const float* wf, const bf16* wh, int off) {
    if (WSB) return *(const bf16x8*)(wh + off);
    return ldg8(wf + off);
}
static __device__ __forceinline__ bf16x4 pk4b(f32x4 v, float4 b) {
    bf16x4 r; r[0]=(bf16)(v[0]+b.x); r[1]=(bf16)(v[1]+b.y);
    r[2]=(bf16)(v[2]+b.z); r[3]=(bf16)(v[3]+b.w); return r;
}
static __device__ __forceinline__ bf16x4 pk4bs(f32x4 v, float4 b, float s) {
    bf16x4 r; r[0]=(bf16)((v[0]+b.x)*s); r[1]=(bf16)((v[1]+b.y)*s);
    r[2]=(bf16)((v[2]+b.z)*s); r[3]=(bf16)((v[3]+b.w)*s); return r;
}
static __device__ __forceinline__ bf16x4 pk4c(f32x4 v, float b) {
    bf16x4 r; r[0]=(bf16)(v[0]+b); r[1]=(bf16)(v[1]+b);
    r[2]=(bf16)(v[2]+b); r[3]=(bf16)(v[3]+b); return r;
}
static __device__ __forceinline__ bf16x4 pk4s(f32x4 v, float s) {
    bf16x4 r; r[0]=(bf16)(v[0]*s); r[1]=(bf16)(v[1]*s);
    r[2]=(bf16)(v[2]*s); r[3]=(bf16)(v[3]*s); return r;
}
static __device__ __forceinline__ bf16x4 pk4(f32x4 v) {
    bf16x4 r; r[0]=(bf16)v[0]; r[1]=(bf16)v[1]; r[2]=(bf16)v[2]; r[3]=(bf16)v[3]; return r;
}
static __device__ __forceinline__ bf16x8 cat8(bf16x4 a, bf16x4 b) {
    bf16x8 r; r[0]=a[0]; r[1]=a[1]; r[2]=a[2]; r[3]=a[3];
    r[4]=b[0]; r[5]=b[1]; r[6]=b[2]; r[7]=b[3]; return r;
}
static __device__ __forceinline__ f32x4 splat4(float b) {
    f32x4 r; r[0]=b; r[1]=b; r[2]=b; r[3]=b; return r;
}
static __device__ __forceinline__ f32x4 f4of(float4 b) {
    f32x4 r; r[0]=b.x; r[1]=b.y; r[2]=b.z; r[3]=b.w; return r;
}
static __device__ __forceinline__ f32x4 f4ofs(float4 b, float s) {
    f32x4 r; r[0]=b.x*s; r[1]=b.y*s; r[2]=b.z*s; r[3]=b.w*s; return r;
}

// ---------------------------------------------------------------------------
// Setup: parameter tables incl. frag-layout (lane-coalesced) copies.
// hqkvf Q-section is pre-scaled by 32^-0.5.
// ---------------------------------------------------------------------------
__global__ __launch_bounds__(256) void setup_ws(const float* __restrict__ rpb,
                                                const float* __restrict__ qkv_w,
                                                const float* __restrict__ proj_w,
                                                float* __restrict__ wbias,
                                                bf16* __restrict__ hqkv,
                                                bf16* __restrict__ hproj,
                                                float* __restrict__ wbf,
                                                bf16* __restrict__ hqkvf,
                                                bf16* __restrict__ hprojf) {
    const int e = blockIdx.x * 256 + threadIdx.x;   // 0..163839
    if (e < 16384) {
        const int h = e >> 12, i = (e >> 6) & 63, j = e & 63;
        const int dy = (i >> 3) - (j >> 3) + 7;
        const int dx = (i & 7)  - (j & 7)  + 7;
        wbias[e] = rpb[(dy * 15 + dx) * 4 + h];
    } else if (e < 65536) {
        const int i = e - 16384;
        hqkv[i] = (bf16)qkv_w[i];
    } else if (e < 81920) {
        const int i = e - 65536;
        hproj[i] = (bf16)proj_w[i];
    } else if (e < 98304) {
        const int t = e - 81920;
        const int r = t & 3, lane = (t >> 2) & 63;
        const int m = (t >> 8) & 3, n = (t >> 10) & 3, h = t >> 12;
        const int lo = lane & 15, hi = lane >> 4;
        const int i_ = n*16 + lo;
        const int j_ = (m >> 1)*32 + hi*8 + (m & 1)*4 + r;
        const int dy = (i_ >> 3) - (j_ >> 3) + 7;
        const int dx = (i_ & 7)  - (j_ & 7)  + 7;
        wbf[t] = rpb[(dy * 15 + dx) * 4 + h];
    } else if (e < 147456) {
        const int t = e - 98304;
        const int el = t & 7, lane = (t >> 3) & 63;
        const int a = (t >> 9) & 1, kb = (t >> 10) & 3;
        const int h = (t >> 12) & 3, ph = t >> 14;
        const int lo = lane & 15, hi = lane >> 4;
        const int prow = ((lo >> 2) << 3) + (lo & 3);
        const int row = (ph == 2) ? (256 + h*32 + a*16 + lo)
                                  : (ph*128 + h*32 + prow + a*4);
        const int col = kb*32 + hi*8 + el;
        float wv_ = qkv_w[row*128 + col];
        if (ph == 0) wv_ *= 0.17677669529663687f;   // fold attention scale into Wq
        hqkvf[t] = (bf16)wv_;
    } else {
        const int t = e - 147456;
        const int el = t & 7, lane = (t >> 3) & 63;
        const int tA = (t >> 9) & 3, kb = (t >> 11) & 3, oh = t >> 13;
        const int lo = lane & 15, hi = lane >> 4;
        const int row = oh*64 + tA*16 + lo;
        const int col = kb*32 + hi*8 + el;
        hprojf[t] = (bf16)proj_w[row*128 + col];
    }
}

// ---------------------------------------------------------------------------
// Fused gather + QKV + attention. 256 thr = 4 waves = 4 heads, one barrier,
// __launch_bounds__(256,5): 5 blocks/CU for latency hiding (VGPR cap 102).
// Gather: float4 loads (roll-aligned), quad-channel bf16x4 LDS writes.
// Trims: biases as MFMA C-init, SCALE folded into Wq, no-max-sub softmax.
// ---------------------------------------------------------------------------
__global__ __launch_bounds__(256, 5)
void qkv_attn(const float* __restrict__ x, const float* __restrict__ qkv_b,
              const bf16* __restrict__ hqkvf, const float* __restrict__ wbf,
              bf16* __restrict__ obuf)
{
    __shared__ char sX[16384];   // [64 tok][256B ch] bf16, col ^ SW(tok)
    const int tid  = threadIdx.x;
    const int lane = tid & 63;
    const int h    = tid >> 6;
    const int lo   = lane & 15;
    const int hi   = lane >> 4;

    const int bid   = blockIdx.x;        // == win index
    const int batch = bid & 7;
    const int wrem  = bid >> 3;
    const int wy    = wrem / NWX;
    const int wx    = wrem - wy * NWX;

    const f32x4 FZ = {0.f, 0.f, 0.f, 0.f};
    const float SCALE = 0.17677669529663687f;
    const int prow = ((lo >> 2) << 3) + (lo & 3);

    // ---- gather+roll -> LDS: 512 (chq,row,w4) tiles, 4 planes per tile ----
    {
        const int hbase = wy*8 + 4;
        const int wbase = wx*8 + 4;
        #pragma unroll
        for (int k = 0; k < 2; ++k) {
            const int id  = k*256 + tid;     // 0..511
            const int w4  = id & 1;
            const int row = (id >> 1) & 7;
            const int chq = id >> 4;         // channel quad 0..31
            int hh = hbase + row;  if (hh >= HIMG) hh -= HIMG;
            int ww = wbase + w4*4; if (ww >= HIMG) ww -= HIMG;
            const float* p0 = x + (size_t)(batch*128 + chq*4) * HWSZ + hh*HIMG + ww;
            const float4 a = *(const float4*)p0;
            const float4 b = *(const float4*)(p0 + HWSZ);
            const float4 c = *(const float4*)(p0 + 2*HWSZ);
            const float4 d = *(const float4*)(p0 + 3*HWSZ);
            const int t0 = row*8 + w4*4;
            #pragma unroll
            for (int e = 0; e < 4; ++e) {
                const int t = t0 + e;
                bf16x4 pr;
                pr[0] = (bf16)(&a.x)[e]; pr[1] = (bf16)(&b.x)[e];
                pr[2] = (bf16)(&c.x)[e]; pr[3] = (bf16)(&d.x)[e];
                *(bf16x4*)(sX + t*256 + ((8*chq) ^ SW(t))) = pr;
            }
        }
    }
    __syncthreads();   // only barrier

    const bf16* const wQ = hqkvf + h * 4096;            // pre-scaled
    const bf16* const wK = hqkvf + 16384 + h * 4096;
    const bf16* const wV = hqkvf + 32768 + h * 4096;

    bf16x8 qf[4], kf[4], vf[2][2];

    // ---- Q^T = (S*Wq) @ X^T, bias via C-init ----
    {
        const float4 b0 = *(const float4*)(qkv_b + h*32 + hi*8);
        const float4 b1 = *(const float4*)(qkv_b + h*32 + hi*8 + 4);
        const f32x4 c0 = f4ofs(b0, SCALE);
        const f32x4 c1 = f4ofs(b1, SCALE);
        f32x4 acc[2][4];
        #pragma unroll
        for (int n = 0; n < 4; ++n) { acc[0][n] = c0; acc[1][n] = c1; }
        #pragma unroll
        for (int kb = 0; kb < 4; ++kb) {
            bf16x8 xf[4];
            #pragma unroll
            for (int n = 0; n < 4; ++n) {
                const int row = n*16 + lo;
                xf[n] = *(const bf16x8*)(sX + row*256 + ((kb*64 + hi*16) ^ SW(row)));
            }
            const bf16x8 w0 = *(const bf16x8*)(wQ + (kb*2    )*512 + lane*8);
            const bf16x8 w1 = *(const bf16x8*)(wQ + (kb*2 + 1)*512 + lane*8);
            #pragma unroll
            for (int n = 0; n < 4; ++n) {
                acc[0][n] = MFMA(w0, xf[n], acc[0][n]);
                acc[1][n] = MFMA(w1, xf[n], acc[1][n]);
            }
        }
        #pragma unroll
        for (int n = 0; n < 4; ++n)
            qf[n] = cat8(pk4(acc[0][n]), pk4(acc[1][n]));
    }

    // ---- K^T and V merged (shared permuted-row X frags), bias via C-init ----
    {
        const float4 k0 = *(const float4*)(qkv_b + 128 + h*32 + hi*8);
        const float4 k1 = *(const float4*)(qkv_b + 128 + h*32 + hi*8 + 4);
        const float bv0 = qkv_b[256 + h*32 + lo];
        const float bv1 = qkv_b[256 + h*32 + 16 + lo];
        const f32x4 ck0 = f4of(k0), ck1 = f4of(k1);
        const f32x4 cv0 = splat4(bv0), cv1 = splat4(bv1);
        f32x4 ak[2][4], av[4][2];
        #pragma unroll
        for (int m = 0; m < 4; ++m) {
            ak[0][m] = ck0; ak[1][m] = ck1; av[m][0] = cv0; av[m][1] = cv1;
        }
        #pragma unroll
        for (int kb = 0; kb < 4; ++kb) {
            bf16x8 xf[4];
            #pragma unroll
            for (int m = 0; m < 4; ++m) {
                const int row = (m >> 1)*32 + (m & 1)*4 + prow;
                xf[m] = *(const bf16x8*)(sX + row*256 + ((kb*64 + hi*16) ^ SW(row)));
            }
            const bf16x8 wk0 = *(const bf16x8*)(wK + (kb*2    )*512 + lane*8);
            const bf16x8 wk1 = *(const bf16x8*)(wK + (kb*2 + 1)*512 + lane*8);
            const bf16x8 wv0 = *(const bf16x8*)(wV + (kb*2    )*512 + lane*8);
            const bf16x8 wv1 = *(const bf16x8*)(wV + (kb*2 + 1)*512 + lane*8);
            #pragma unroll
            for (int m = 0; m < 4; ++m) {
                ak[0][m] = MFMA(wk0, xf[m], ak[0][m]);
                ak[1][m] = MFMA(wk1, xf[m], ak[1][m]);
                av[m][0] = MFMA(xf[m], wv0, av[m][0]);
                av[m][1] = MFMA(xf[m], wv1, av[m][1]);
            }
        }
        #pragma unroll
        for (int m = 0; m < 4; ++m)
            kf[m] = cat8(pk4(ak[0][m]), pk4(ak[1][m]));
        #pragma unroll
        for (int kb = 0; kb < 2; ++kb) {
            vf[0][kb] = cat8(pk4(av[kb*2][0]), pk4(av[kb*2 + 1][0]));
            vf[1][kb] = cat8(pk4(av[kb*2][1]), pk4(av[kb*2 + 1][1]));
        }
    }

    // ---- S^T = K @ Q^T + (bias+mask as C-init); softmax (no max-sub) ----
    const bool ey = (wy == 23), ex = (wx == 23);
    const bool edge = ey || ex;
    const float* const wbh = wbf + h * 4096;
    bf16x8 pf[2][4];
    float rinv[4];
    #pragma unroll
    for (int n = 0; n < 4; ++n) {
        const int i_ = n*16 + lo;
        const int yi = i_ >> 3, xi = i_ & 7;
        const int ri = (ey ? (yi < 4 ? 1 : 2) : 0) * 3 + (ex ? (xi < 4 ? 1 : 2) : 0);
        f32x4 sc[4];
        #pragma unroll
        for (int m = 0; m < 4; ++m) {
            f32x4 ci = *(const f32x4*)(wbh + (n*4 + m)*256 + lane*4);
            if (edge) {
                #pragma unroll
                for (int r = 0; r < 4; ++r) {
                    const int j_ = (m >> 1)*32 + hi*8 + (m & 1)*4 + r;
                    const int yj = j_ >> 3, xj = j_ & 7;
                    const int rj = (ey ? (yj < 4 ? 1 : 2) : 0) * 3 + (ex ? (xj < 4 ? 1 : 2) : 0);
                    ci[r] += (ri != rj) ? -100.0f : 0.0f;
                }
            }
            sc[m] = MFMA(kf[m], qf[n], ci);
        }
        float sum = 0.f;
        #pragma unroll
        for (int m = 0; m < 4; ++m)
            #pragma unroll
            for (int r = 0; r < 4; ++r) {
                const float p = __expf(sc[m][r]);
                sc[m][r] = p; sum += p;
            }
        sum += __shfl_xor(sum, 16);
        sum += __shfl_xor(sum, 32);
        rinv[n] = 1.0f / sum;
        pf[0][n] = cat8(pk4(sc[0]), pk4(sc[1]));
        pf[1][n] = cat8(pk4(sc[2]), pk4(sc[3]));
    }

    // ---- O^T = V^T @ P^T; coalesced frag store ----
    f32x4 o0[2][4];
    #pragma unroll
    for (int o = 0; o < 2; ++o)
        #pragma unroll
        for (int n = 0; n < 4; ++n) o0[o][n] = FZ;
    #pragma unroll
    for (int kb = 0; kb < 2; ++kb)
        #pragma unroll
        for (int o = 0; o < 2; ++o)
            #pragma unroll
            for (int n = 0; n < 4; ++n)
                o0[o][n] = MFMA(vf[o][kb], pf[kb][n], o0[o][n]);

    bf16* const ob = obuf + (size_t)bid * 8192 + h * 2048;
    #pragma unroll
    for (int n = 0; n < 4; ++n)
        #pragma unroll
        for (int o = 0; o < 2; ++o)
            *(bf16x4*)(ob + (n*2 + o)*256 + lane*4) = pk4s(o0[o][n], rinv[n]);
}

// ---------------------------------------------------------------------------
// Projection by image rows (unchanged).
// ---------------------------------------------------------------------------
__global__ __launch_bounds__(512, 3)
void proj_rows(const bf16* __restrict__ obuf, const bf16* __restrict__ hprojf,
               const float* __restrict__ proj_b, float* __restrict__ out)
{
    __shared__ char sR[49152];   // [192 tok][256B bf16], col ^ SW(tok)
    const int tid  = threadIdx.x;
    const int lane = tid & 63;
    const int wv   = tid >> 6;
    const int lo   = lane & 15;
    const int hi   = lane >> 4;

    const int bid   = blockIdx.x;        // 1536 = 8 batch x 192 rows
    const int batch = bid & 7;
    const int hh    = bid >> 3;          // output row 0..191
    int hr = hh + 188; if (hr >= 192) hr -= 192;   // rolled-frame row
    const int wy = hr >> 3, iy = hr & 7;
    const int n_ = iy >> 1;

    #pragma unroll
    for (int k = 0; k < 6; ++k) {
        const int i  = tid + k*512;      // 0..3071
        const int wr = i >> 4;           // rolled-frame col
        const int cc = i & 15;           // 8-channel chunk
        const int wxx = wr >> 3, ix = wr & 7;
        const int win = (wy*NWX + wxx)*8 + batch;
        const int lo2 = (iy & 1)*8 + ix;
        const int hg = cc >> 2, oo = (cc >> 1) & 1, hp = cc & 1;
        const bf16* bp = obuf + (size_t)win*8192 + hg*2048 + (n_*2 + oo)*256;
        const bf16x4 p0 = *(const bf16x4*)(bp + ((hp*2    )*16 + lo2)*4);
        const bf16x4 p1 = *(const bf16x4*)(bp + ((hp*2 + 1)*16 + lo2)*4);
        int wo = wr + 4; if (wo >= 192) wo -= 192;
        *(bf16x8*)(sR + wo*256 + ((cc*16) ^ SW(wo))) = cat8(p0, p1);
    }
    __syncthreads();

    const int q  = wv >> 1;
    const int oh = wv & 1;
    const f32x4 FZ = {0.f, 0.f, 0.f, 0.f};
    f32x4 acc[4][3];
    #pragma unroll
    for (int tA = 0; tA < 4; ++tA)
        #pragma unroll
        for (int tN = 0; tN < 3; ++tN) acc[tA][tN] = FZ;

    #pragma unroll
    for (int kb = 0; kb < 4; ++kb) {
        bf16x8 of[3];
        #pragma unroll
        for (int tN = 0; tN < 3; ++tN) {
            const int tok = q*48 + tN*16 + lo;
            of[tN] = *(const bf16x8*)(sR + tok*256 + ((kb*64 + hi*16) ^ SW(tok)));
        }
        bf16x8 wf[4];
        #pragma unroll
        for (int tA = 0; tA < 4; ++tA)
            wf[tA] = *(const bf16x8*)(hprojf + (size_t)(((oh*4 + kb)*4 + tA)*64 + lane)*8);
        #pragma unroll
        for (int tA = 0; tA < 4; ++tA)
            #pragma unroll
            for (int tN = 0; tN < 3; ++tN)
                acc[tA][tN] = MFMA(of[tN], wf[tA], acc[tA][tN]);
    }

    #pragma unroll
    for (int tA = 0; tA < 4; ++tA) {
        const int oc = oh*64 + tA*16 + lo;
        const float pb = proj_b[oc];
        float* const orow = out + (size_t)(batch*128 + oc) * HWSZ + hh*HIMG;
        #pragma unroll
        for (int tN = 0; tN < 3; ++tN) {
            const int tb = q*48 + tN*16 + hi*4;
            float4 v;
            v.x = acc[tA][tN][0] + pb;
            v.y = acc[tA][tN][1] + pb;
            v.z = acc[tA][tN][2] + pb;
            v.w = acc[tA][tN][3] + pb;
            *(float4*)(orow + tb) = v;
        }
    }
}

// ---------------------------------------------------------------------------
// Fallback: fused one-wave-per-window kernel (round-6), for small workspaces.
// ---------------------------------------------------------------------------
template<int WSB>
__global__ __launch_bounds__(64, 2)
void swin_fused(const float* __restrict__ x, const float* __restrict__ qkv_w,
                const float* __restrict__ qkv_b, const float* __restrict__ proj_w,
                const float* __restrict__ proj_b, const float* __restrict__ rpb,
                const float* __restrict__ wb, const bf16* __restrict__ hqkv,
                const bf16* __restrict__ hproj, float* __restrict__ out)
{
    __shared__ char sX[16384];

    const int lane = threadIdx.x & 63;
    const int lo   = lane & 15;
    const int hi   = lane >> 4;

    const int bid   = blockIdx.x;
    const int batch = bid & 7;
    const int wrem  = bid >> 3;
    const int wy    = wrem / NWX;
    const int wx    = wrem - wy * NWX;
    const long xbase = (long)batch * 128 * HWSZ;

    const f32x4 FZ = {0.f, 0.f, 0.f, 0.f};
    const float SCALE = 0.17677669529663687f;
    const int prow = ((lo >> 2) << 3) + (lo & 3);

    {
        int hh = wy*8 + (lane >> 3) + 4; if (hh >= HIMG) hh -= HIMG;
        int ww = wx*8 + (lane & 7)  + 4; if (ww >= HIMG) ww -= HIMG;
        const float* xp = x + xbase + hh * HIMG + ww;
        char* const wp = sX + lane * 256;
        const int swz = SW(lane);
        #pragma unroll
        for (int g = 0; g < 16; ++g) {
            bf16x8 v;
            #pragma unroll
            for (int e = 0; e < 8; ++e) v[e] = (bf16)xp[(g*8 + e) * HWSZ];
            *(bf16x8*)(wp + ((16*g) ^ swz)) = v;
        }
    }

    const bool ey = (wy == 23), ex = (wx == 23);
    const bool edge = ey || ex;

    bf16x4 ob[4][2][4];

    #pragma unroll
    for (int h = 0; h < 4; ++h) {
        bf16x8 qf[4], kf[4];
        {
            f32x4 acc[2][4];
            #pragma unroll
            for (int a = 0; a < 2; ++a)
                #pragma unroll
                for (int n = 0; n < 4; ++n) acc[a][n] = FZ;
            #pragma unroll
            for (int kb = 0; kb < 4; ++kb) {
                bf16x8 xf[4];
                #pragma unroll
                for (int n = 0; n < 4; ++n) {
                    const int row = n*16 + lo;
                    xf[n] = *(const bf16x8*)(sX + row*256 + ((kb*64 + hi*16) ^ SW(row)));
                }
                const int coff = kb*32 + hi*8;
                const bf16x8 w0 = ldw<WSB>(qkv_w, hqkv, (h*32 + prow    ) * 128 + coff);
                const bf16x8 w1 = ldw<WSB>(qkv_w, hqkv, (h*32 + prow + 4) * 128 + coff);
                #pragma unroll
                for (int n = 0; n < 4; ++n) {
                    acc[0][n] = MFMA(w0, xf[n], acc[0][n]);
                    acc[1][n] = MFMA(w1, xf[n], acc[1][n]);
                }
            }
            const float4 b0 = *(const float4*)(qkv_b + h*32 + hi*8);
            const float4 b1 = *(const float4*)(qkv_b + h*32 + hi*8 + 4);
            #pragma unroll
            for (int n = 0; n < 4; ++n)
                qf[n] = cat8(pk4bs(acc[0][n], b0, SCALE), pk4bs(acc[1][n], b1, SCALE));
        }
        {
            f32x4 ak[2][4];
            #pragma unroll
            for (int a = 0; a < 2; ++a)
                #pragma unroll
                for (int m = 0; m < 4; ++m) ak[a][m] = FZ;
            #pragma unroll
            for (int kb = 0; kb < 4; ++kb) {
                bf16x8 xf[4];
                #pragma unroll
                for (int m = 0; m < 4; ++m) {
                    const int row = (m >> 1)*32 + (m & 1)*4 + prow;
                    xf[m] = *(const bf16x8*)(sX + row*256 + ((kb*64 + hi*16) ^ SW(row)));
                }
                const int coff = kb*32 + hi*8;
                const bf16x8 w0 = ldw<WSB>(qkv_w, hqkv, (128 + h*32 + prow    ) * 128 + coff);
                const bf16x8 w1 = ldw<WSB>(qkv_w, hqkv, (128 + h*32 + prow + 4) * 128 + coff);
                #pragma unroll
                for (int m = 0; m < 4; ++m) {
                    ak[0][m] = MFMA(w0, xf[m], ak[0][m]);
                    ak[1][m] = MFMA(w1, xf[m], ak[1][m]);
                }
            }
            const float4 b0 = *(const float4*)(qkv_b + 128 + h*32 + hi*8);
            const float4 b1 = *(const float4*)(qkv_b + 128 + h*32 + hi*8 + 4);
            #pragma unroll
            for (int m = 0; m < 4; ++m)
                kf[m] = cat8(pk4b(ak[0][m], b0), pk4b(ak[1][m], b1));
        }

        f32x4 s2[4][4];
        const float* wbh = wb + h * 4096;
        #pragma unroll
        for (int n = 0; n < 4; ++n) {
            const int i_ = n*16 + lo;
            const int yi = i_ >> 3, xi = i_ & 7;
            const int ri = (ey ? (yi < 4 ? 1 : 2) : 0) * 3 + (ex ? (xi < 4 ? 1 : 2) : 0);
            #pragma unroll
            for (int m = 0; m < 4; ++m) {
                const int j0 = (m >> 1)*32 + hi*8 + (m & 1)*4;
                f32x4 ci;
                if (WSB) ci = *(const f32x4*)(wbh + i_*64 + j0);
                else {
                    #pragma unroll
                    for (int r = 0; r < 4; ++r) {
                        const int j_ = j0 + r;
                        ci[r] = rpb[((yi - (j_ >> 3) + 7) * 15 + (xi - (j_ & 7) + 7)) * 4 + h];
                    }
                }
                if (edge) {
                    #pragma unroll
                    for (int r = 0; r < 4; ++r) {
                        const int j_ = j0 + r;
                        const int yj = j_ >> 3, xj = j_ & 7;
                        const int rj = (ey ? (yj < 4 ? 1 : 2) : 0) * 3 + (ex ? (xj < 4 ? 1 : 2) : 0);
                        ci[r] += (ri != rj) ? -100.0f : 0.0f;
                    }
                }
                s2[m][n] = MFMA(kf[m], qf[n], ci);
            }
        }
        float rinv[4];
        #pragma unroll
        for (int n = 0; n < 4; ++n) {
            float mx = -1e30f;
            #pragma unroll
            for (int m = 0; m < 4; ++m)
                #pragma unroll
                for (int r = 0; r < 4; ++r) mx = fmaxf(mx, s2[m][n][r]);
            mx = fmaxf(mx, __shfl_xor(mx, 16));
            mx = fmaxf(mx, __shfl_xor(mx, 32));
            float sum = 0.f;
            #pragma unroll
            for (int m = 0; m < 4; ++m)
                #pragma unroll
                for (int r = 0; r < 4; ++r) {
                    const float p = __expf(s2[m][n][r] - mx);
                    s2[m][n][r] = p; sum += p;
                }
            sum += __shfl_xor(sum, 16);
            sum += __shfl_xor(sum, 32);
            rinv[n] = 1.0f / sum;
        }
        bf16x8 pf[2][4];
        #pragma unroll
        for (int kb = 0; kb < 2; ++kb)
            #pragma unroll
            for (int n = 0; n < 4; ++n)
                pf[kb][n] = cat8(pk4(s2[kb*2][n]), pk4(s2[kb*2 + 1][n]));

        bf16x8 vf[2][2];
        {
            f32x4 av[4][2];
            #pragma unroll
            for (int m = 0; m < 4; ++m) { av[m][0] = FZ; av[m][1] = FZ; }
            #pragma unroll
            for (int kb = 0; kb < 4; ++kb) {
                bf16x8 xv[4];
                #pragma unroll
                for (int m = 0; m < 4; ++m) {
                    const int row = (m >> 1)*32 + (m & 1)*4 + prow;
                    xv[m] = *(const bf16x8*)(sX + row*256 + ((kb*64 + hi*16) ^ SW(row)));
                }
                const int coff = kb*32 + hi*8;
                const bf16x8 w0 = ldw<WSB>(qkv_w, hqkv, (256 + h*32 + lo)      * 128 + coff);
                const bf16x8 w1 = ldw<WSB>(qkv_w, hqkv, (256 + h*32 + 16 + lo) * 128 + coff);
                #pragma unroll
                for (int m = 0; m < 4; ++m) {
                    av[m][0] = MFMA(xv[m], w0, av[m][0]);
                    av[m][1] = MFMA(xv[m], w1, av[m][1]);
                }
            }
            const float bv0 = qkv_b[256 + h*32 + lo];
            const float bv1 = qkv_b[256 + h*32 + 16 + lo];
            #pragma unroll
            for (int kb = 0; kb < 2; ++kb) {
                vf[0][kb] = cat8(pk4c(av[kb*2][0], bv0), pk4c(av[kb*2 + 1][0], bv0));
                vf[1][kb] = cat8(pk4c(av[kb*2][1], bv1), pk4c(av[kb*2 + 1][1], bv1));
            }
        }
        {
            f32x4 o0[2][4];
            #pragma unroll
            for (int o = 0; o < 2; ++o)
                #pragma unroll
                for (int n = 0; n < 4; ++n) o0[o][n] = FZ;
            #pragma unroll
            for (int kb = 0; kb < 2; ++kb)
                #pragma unroll
                for (int o = 0; o < 2; ++o)
                    #pragma unroll
                    for (int n = 0; n < 4; ++n)
                        o0[o][n] = MFMA(vf[o][kb], pf[kb][n], o0[o][n]);
            #pragma unroll
            for (int o = 0; o < 2; ++o)
                #pragma unroll
                for (int n = 0; n < 4; ++n)
                    ob[h][o][n] = pk4s(o0[o][n], rinv[n]);
        }
    }

    #pragma unroll
    for (int h = 0; h < 4; ++h)
        #pragma unroll
        for (int o = 0; o < 2; ++o) {
            const int cb = h*64 + o*32 + hi*8;
            #pragma unroll
            for (int n = 0; n < 4; ++n) {
                const int t = n*16 + lo;
                *(bf16x4*)(sX + t*256 + (cb ^ SW(t))) = ob[h][o][n];
            }
        }

    #pragma unroll
    for (int c4 = 0; c4 < 4; ++c4) {
        f32x4 pr[2][4];
        #pragma unroll
        for (int a = 0; a < 2; ++a)
            #pragma unroll
            for (int n = 0; n < 4; ++n) pr[a][n] = FZ;
        #pragma unroll
        for (int kb = 0; kb < 4; ++kb) {
            bf16x8 af[4];
            #pragma unroll
            for (int n = 0; n < 4; ++n) {
                const int row = n*16 + lo;
                af[n] = *(const bf16x8*)(sX + row*256 + ((kb*64 + hi*16) ^ SW(row)));
            }
            const int coff = kb*32 + hi*8;
            const bf16x8 w0 = ldw<WSB>(proj_w, hproj, (c4*32 + lo)      * 128 + coff);
            const bf16x8 w1 = ldw<WSB>(proj_w, hproj, (c4*32 + 16 + lo) * 128 + coff);
            #pragma unroll
            for (int n = 0; n < 4; ++n) {
                pr[0][n] = MFMA(w0, af[n], pr[0][n]);
                pr[1][n] = MFMA(w1, af[n], pr[1][n]);
            }
        }
        #pragma unroll
        for (int a = 0; a < 2; ++a) {
            const int ocb = c4*32 + a*16 + hi*4;
            const float4 pb = *(const float4*)(proj_b + ocb);
            #pragma unroll
            for (int n = 0; n < 4; ++n) {
                const int t = n*16 + lo;
                int hh = wy*8 + (t >> 3) + 4; if (hh >= HIMG) hh -= HIMG;
                int ww = wx*8 + (t & 7)  + 4; if (ww >= HIMG) ww -= HIMG;
                float* op = out + (long)(batch*128 + ocb) * HWSZ + hh*HIMG + ww;
                op[0]      = pr[a][n][0] + pb.x;
                op[HWSZ]   = pr[a][n][1] + pb.y;
                op[2*HWSZ] = pr[a][n][2] + pb.z;
                op[3*HWSZ] = pr[a][n][3] + pb.w;
            }
        }
    }
}

extern "C" void kernel_launch(void* const* d_in, const int* in_sizes, int n_in,
                              void* d_out, int out_size, void* d_ws, size_t ws_size,
                              hipStream_t stream) {
    const float* x      = (const float*)d_in[0];
    const float* qkv_w  = (const float*)d_in[1];
    const float* qkv_b  = (const float*)d_in[2];
    const float* proj_w = (const float*)d_in[3];
    const float* proj_b = (const float*)d_in[4];
    const float* rpb    = (const float*)d_in[5];
    float* out = (float*)d_out;

    // ws bytes: [0,64K) wbias f32 | [64K,160K) hqkv | [160K,192K) hproj
    //           [192K,256K) wbf f32 | [256K,352K) hqkvf | [352K,384K) hprojf
    //           [384K, +75.5M) obuf
    const size_t SETUP = 393216;
    const size_t OSZ   = (size_t)4608 * 16384;

    float* wbias = (float*)d_ws;
    bf16*  hqkv  = (bf16*)((char*)d_ws + 65536);
    bf16*  hproj = (bf16*)((char*)d_ws + 163840);
    float* wbf   = (float*)((char*)d_ws + 196608);
    bf16*  hqkvf = (bf16*)((char*)d_ws + 262144);
    bf16*  hprojf= (bf16*)((char*)d_ws + 360448);
    bf16*  obuf  = (bf16*)((char*)d_ws + SETUP);

    if (ws_size >= SETUP + OSZ) {
        setup_ws<<<640, 256, 0, stream>>>(rpb, qkv_w, proj_w, wbias, hqkv, hproj,
                                          wbf, hqkvf, hprojf);
        qkv_attn<<<4608, 256, 0, stream>>>(x, qkv_b, hqkvf, wbf, obuf);
        proj_rows<<<1536, 512, 0, stream>>>(obuf, hprojf, proj_b, out);
    } else if (ws_size >= SETUP) {
        setup_ws<<<640, 256, 0, stream>>>(rpb, qkv_w, proj_w, wbias, hqkv, hproj,
                                          wbf, hqkvf, hprojf);
        swin_fused<1><<<4608, 64, 0, stream>>>(x, qkv_w, qkv_b, proj_w, proj_b, rpb,
                                               wbias, hqkv, hproj, out);
    } else {
        swin_fused<0><<<4608, 64, 0, stream>>>(x, qkv_w, qkv_b, proj_w, proj_b, rpb,
                                               nullptr, nullptr, nullptr, out);
    }
}

// Round 15
// 214.662 us; speedup vs baseline: 1.5258x; 1.5258x over previous
//
#include <hip/hip_runtime.h>

#define HIMG 192
#define HWSZ (192*192)
#define NWX  24

typedef __bf16 bf16;
typedef __bf16 bf16x2 __attribute__((ext_vector_type(2)));
typedef __bf16 bf16x4 __attribute__((ext_vector_type(4)));
typedef __bf16 bf16x8 __attribute__((ext_vector_type(8)));
typedef float  f32x4  __attribute__((ext_vector_type(4)));

#define MFMA(a,b,c) __builtin_amdgcn_mfma_f32_16x16x32_bf16((a),(b),(c),0,0,0)
#define SW(r) (((((r)&7) ^ ((((r)>>3)&1)<<2))) << 4)

static __device__ __forceinline__ bf16x8 ldg8(const float* p) {
    const float4 u = ((const float4*)p)[0];
    const float4 v = ((const float4*)p)[1];
    bf16x8 r;
    r[0]=(bf16)u.x; r[1]=(bf16)u.y; r[2]=(bf16)u.z; r[3]=(bf16)u.w;
    r[4]=(bf16)v.x; r[5]=(bf16)v.y; r[6]=(bf16)v.z; r[7]=(bf16)v.w;
    return r;
}
template<int WSB>
static __device__ __forceinline__ bf16x8 ldw(const float* wf, const bf16* wh, int off) {
    if (WSB) return *(const bf16x8*)(wh + off);
    return ldg8(wf + off);
}
static __device__ __forceinline__ bf16x4 pk4b(f32x4 v, float4 b) {
    bf16x4 r; r[0]=(bf16)(v[0]+b.x); r[1]=(bf16)(v[1]+b.y);
    r[2]=(bf16)(v[2]+b.z); r[3]=(bf16)(v[3]+b.w); return r;
}
static __device__ __forceinline__ bf16x4 pk4bs(f32x4 v, float4 b, float s) {
    bf16x4 r; r[0]=(bf16)((v[0]+b.x)*s); r[1]=(bf16)((v[1]+b.y)*s);
    r[2]=(bf16)((v[2]+b.z)*s); r[3]=(bf16)((v[3]+b.w)*s); return r;
}
static __device__ __forceinline__ bf16x4 pk4c(f32x4 v, float b) {
    bf16x4 r; r[0]=(bf16)(v[0]+b); r[1]=(bf16)(v[1]+b);
    r[2]=(bf16)(v[2]+b); r[3]=(bf16)(v[3]+b); return r;
}
static __device__ __forceinline__ bf16x4 pk4s(f32x4 v, float s) {
    bf16x4 r; r[0]=(bf16)(v[0]*s); r[1]=(bf16)(v[1]*s);
    r[2]=(bf16)(v[2]*s); r[3]=(bf16)(v[3]*s); return r;
}
static __device__ __forceinline__ bf16x4 pk4(f32x4 v) {
    bf16x4 r; r[0]=(bf16)v[0]; r[1]=(bf16)v[1]; r[2]=(bf16)v[2]; r[3]=(bf16)v[3]; return r;
}
static __device__ __forceinline__ bf16x8 cat8(bf16x4 a, bf16x4 b) {
    bf16x8 r; r[0]=a[0]; r[1]=a[1]; r[2]=a[2]; r[3]=a[3];
    r[4]=b[0]; r[5]=b[1]; r[6]=b[2]; r[7]=b[3]; return r;
}
static __device__ __forceinline__ f32x4 splat4(float b) {
    f32x4 r; r[0]=b; r[1]=b; r[2]=b; r[3]=b; return r;
}
static __device__ __forceinline__ f32x4 f4of(float4 b) {
    f32x4 r; r[0]=b.x; r[1]=b.y; r[2]=b.z; r[3]=b.w; return r;
}
static __device__ __forceinline__ f32x4 f4ofs(float4 b, float s) {
    f32x4 r; r[0]=b.x*s; r[1]=b.y*s; r[2]=b.z*s; r[3]=b.w*s; return r;
}

// ---------------------------------------------------------------------------
// Setup: parameter tables incl. frag-layout (lane-coalesced) copies.
// hqkvf Q-section is pre-scaled by 32^-0.5.
// ---------------------------------------------------------------------------
__global__ __launch_bounds__(256) void setup_ws(const float* __restrict__ rpb,
                                                const float* __restrict__ qkv_w,
                                                const float* __restrict__ proj_w,
                                                float* __restrict__ wbias,
                                                bf16* __restrict__ hqkv,
                                                bf16* __restrict__ hproj,
                                                float* __restrict__ wbf,
                                                bf16* __restrict__ hqkvf,
                                                bf16* __restrict__ hprojf) {
    const int e = blockIdx.x * 256 + threadIdx.x;   // 0..163839
    if (e < 16384) {
        const int h = e >> 12, i = (e >> 6) & 63, j = e & 63;
        const int dy = (i >> 3) - (j >> 3) + 7;
        const int dx = (i & 7)  - (j & 7)  + 7;
        wbias[e] = rpb[(dy * 15 + dx) * 4 + h];
    } else if (e < 65536) {
        const int i = e - 16384;
        hqkv[i] = (bf16)qkv_w[i];
    } else if (e < 81920) {
        const int i = e - 65536;
        hproj[i] = (bf16)proj_w[i];
    } else if (e < 98304) {
        const int t = e - 81920;
        const int r = t & 3, lane = (t >> 2) & 63;
        const int m = (t >> 8) & 3, n = (t >> 10) & 3, h = t >> 12;
        const int lo = lane & 15, hi = lane >> 4;
        const int i_ = n*16 + lo;
        const int j_ = (m >> 1)*32 + hi*8 + (m & 1)*4 + r;
        const int dy = (i_ >> 3) - (j_ >> 3) + 7;
        const int dx = (i_ & 7)  - (j_ & 7)  + 7;
        wbf[t] = rpb[(dy * 15 + dx) * 4 + h];
    } else if (e < 147456) {
        const int t = e - 98304;
        const int el = t & 7, lane = (t >> 3) & 63;
        const int a = (t >> 9) & 1, kb = (t >> 10) & 3;
        const int h = (t >> 12) & 3, ph = t >> 14;
        const int lo = lane & 15, hi = lane >> 4;
        const int prow = ((lo >> 2) << 3) + (lo & 3);
        const int row = (ph == 2) ? (256 + h*32 + a*16 + lo)
                                  : (ph*128 + h*32 + prow + a*4);
        const int col = kb*32 + hi*8 + el;
        float wv_ = qkv_w[row*128 + col];
        if (ph == 0) wv_ *= 0.17677669529663687f;   // fold attention scale into Wq
        hqkvf[t] = (bf16)wv_;
    } else {
        const int t = e - 147456;
        const int el = t & 7, lane = (t >> 3) & 63;
        const int tA = (t >> 9) & 3, kb = (t >> 11) & 3, oh = t >> 13;
        const int lo = lane & 15, hi = lane >> 4;
        const int row = oh*64 + tA*16 + lo;
        const int col = kb*32 + hi*8 + el;
        hprojf[t] = (bf16)proj_w[row*128 + col];
    }
}

// ---------------------------------------------------------------------------
// Fused gather + QKV + attention. 256 thr = 4 waves = 4 heads, one barrier,
// __launch_bounds__(256,4): cap 128 (measured demand ~80, safe), 4 blocks/CU.
// Gather: float4 loads (roll-aligned), quad-channel bf16x4 LDS writes.
// Trims: biases as MFMA C-init, SCALE folded into Wq, no-max-sub softmax.
// ---------------------------------------------------------------------------
__global__ __launch_bounds__(256, 4)
void qkv_attn(const float* __restrict__ x, const float* __restrict__ qkv_b,
              const bf16* __restrict__ hqkvf, const float* __restrict__ wbf,
              bf16* __restrict__ obuf)
{
    __shared__ char sX[16384];   // [64 tok][256B ch] bf16, col ^ SW(tok)
    const int tid  = threadIdx.x;
    const int lane = tid & 63;
    const int h    = tid >> 6;
    const int lo   = lane & 15;
    const int hi   = lane >> 4;

    const int bid   = blockIdx.x;        // == win index
    const int batch = bid & 7;
    const int wrem  = bid >> 3;
    const int wy    = wrem / NWX;
    const int wx    = wrem - wy * NWX;

    const f32x4 FZ = {0.f, 0.f, 0.f, 0.f};
    const float SCALE = 0.17677669529663687f;
    const int prow = ((lo >> 2) << 3) + (lo & 3);

    // ---- gather+roll -> LDS: 512 (chq,row,w4) tiles, 4 planes per tile ----
    {
        const int hbase = wy*8 + 4;
        const int wbase = wx*8 + 4;
        #pragma unroll
        for (int k = 0; k < 2; ++k) {
            const int id  = k*256 + tid;     // 0..511
            const int w4  = id & 1;
            const int row = (id >> 1) & 7;
            const int chq = id >> 4;         // channel quad 0..31
            int hh = hbase + row;  if (hh >= HIMG) hh -= HIMG;
            int ww = wbase + w4*4; if (ww >= HIMG) ww -= HIMG;
            const float* p0 = x + (size_t)(batch*128 + chq*4) * HWSZ + hh*HIMG + ww;
            const float4 a = *(const float4*)p0;
            const float4 b = *(const float4*)(p0 + HWSZ);
            const float4 c = *(const float4*)(p0 + 2*HWSZ);
            const float4 d = *(const float4*)(p0 + 3*HWSZ);
            const int t0 = row*8 + w4*4;
            #pragma unroll
            for (int e = 0; e < 4; ++e) {
                const int t = t0 + e;
                bf16x4 pr;
                pr[0] = (bf16)(&a.x)[e]; pr[1] = (bf16)(&b.x)[e];
                pr[2] = (bf16)(&c.x)[e]; pr[3] = (bf16)(&d.x)[e];
                *(bf16x4*)(sX + t*256 + ((8*chq) ^ SW(t))) = pr;
            }
        }
    }
    __syncthreads();   // only barrier

    const bf16* const wQ = hqkvf + h * 4096;            // pre-scaled
    const bf16* const wK = hqkvf + 16384 + h * 4096;
    const bf16* const wV = hqkvf + 32768 + h * 4096;

    bf16x8 qf[4], kf[4], vf[2][2];

    // ---- Q^T = (S*Wq) @ X^T, bias via C-init ----
    {
        const float4 b0 = *(const float4*)(qkv_b + h*32 + hi*8);
        const float4 b1 = *(const float4*)(qkv_b + h*32 + hi*8 + 4);
        const f32x4 c0 = f4ofs(b0, SCALE);
        const f32x4 c1 = f4ofs(b1, SCALE);
        f32x4 acc[2][4];
        #pragma unroll
        for (int n = 0; n < 4; ++n) { acc[0][n] = c0; acc[1][n] = c1; }
        #pragma unroll
        for (int kb = 0; kb < 4; ++kb) {
            bf16x8 xf[4];
            #pragma unroll
            for (int n = 0; n < 4; ++n) {
                const int row = n*16 + lo;
                xf[n] = *(const bf16x8*)(sX + row*256 + ((kb*64 + hi*16) ^ SW(row)));
            }
            const bf16x8 w0 = *(const bf16x8*)(wQ + (kb*2    )*512 + lane*8);
            const bf16x8 w1 = *(const bf16x8*)(wQ + (kb*2 + 1)*512 + lane*8);
            #pragma unroll
            for (int n = 0; n < 4; ++n) {
                acc[0][n] = MFMA(w0, xf[n], acc[0][n]);
                acc[1][n] = MFMA(w1, xf[n], acc[1][n]);
            }
        }
        #pragma unroll
        for (int n = 0; n < 4; ++n)
            qf[n] = cat8(pk4(acc[0][n]), pk4(acc[1][n]));
    }

    // ---- K^T and V merged (shared permuted-row X frags), bias via C-init ----
    {
        const float4 k0 = *(const float4*)(qkv_b + 128 + h*32 + hi*8);
        const float4 k1 = *(const float4*)(qkv_b + 128 + h*32 + hi*8 + 4);
        const float bv0 = qkv_b[256 + h*32 + lo];
        const float bv1 = qkv_b[256 + h*32 + 16 + lo];
        const f32x4 ck0 = f4of(k0), ck1 = f4of(k1);
        const f32x4 cv0 = splat4(bv0), cv1 = splat4(bv1);
        f32x4 ak[2][4], av[4][2];
        #pragma unroll
        for (int m = 0; m < 4; ++m) {
            ak[0][m] = ck0; ak[1][m] = ck1; av[m][0] = cv0; av[m][1] = cv1;
        }
        #pragma unroll
        for (int kb = 0; kb < 4; ++kb) {
            bf16x8 xf[4];
            #pragma unroll
            for (int m = 0; m < 4; ++m) {
                const int row = (m >> 1)*32 + (m & 1)*4 + prow;
                xf[m] = *(const bf16x8*)(sX + row*256 + ((kb*64 + hi*16) ^ SW(row)));
            }
            const bf16x8 wk0 = *(const bf16x8*)(wK + (kb*2    )*512 + lane*8);
            const bf16x8 wk1 = *(const bf16x8*)(wK + (kb*2 + 1)*512 + lane*8);
            const bf16x8 wv0 = *(const bf16x8*)(wV + (kb*2    )*512 + lane*8);
            const bf16x8 wv1 = *(const bf16x8*)(wV + (kb*2 + 1)*512 + lane*8);
            #pragma unroll
            for (int m = 0; m < 4; ++m) {
                ak[0][m] = MFMA(wk0, xf[m], ak[0][m]);
                ak[1][m] = MFMA(wk1, xf[m], ak[1][m]);
                av[m][0] = MFMA(xf[m], wv0, av[m][0]);
                av[m][1] = MFMA(xf[m], wv1, av[m][1]);
            }
        }
        #pragma unroll
        for (int m = 0; m < 4; ++m)
            kf[m] = cat8(pk4(ak[0][m]), pk4(ak[1][m]));
        #pragma unroll
        for (int kb = 0; kb < 2; ++kb) {
            vf[0][kb] = cat8(pk4(av[kb*2][0]), pk4(av[kb*2 + 1][0]));
            vf[1][kb] = cat8(pk4(av[kb*2][1]), pk4(av[kb*2 + 1][1]));
        }
    }

    // ---- S^T = K @ Q^T + (bias+mask as C-init); softmax (no max-sub) ----
    const bool ey = (wy == 23), ex = (wx == 23);
    const bool edge = ey || ex;
    const float* const wbh = wbf + h * 4096;
    bf16x8 pf[2][4];
    float rinv[4];
    #pragma unroll
    for (int n = 0; n < 4; ++n) {
        const int i_ = n*16 + lo;
        const int yi = i_ >> 3, xi = i_ & 7;
        const int ri = (ey ? (yi < 4 ? 1 : 2) : 0) * 3 + (ex ? (xi < 4 ? 1 : 2) : 0);
        f32x4 sc[4];
        #pragma unroll
        for (int m = 0; m < 4; ++m) {
            f32x4 ci = *(const f32x4*)(wbh + (n*4 + m)*256 + lane*4);
            if (edge) {
                #pragma unroll
                for (int r = 0; r < 4; ++r) {
                    const int j_ = (m >> 1)*32 + hi*8 + (m & 1)*4 + r;
                    const int yj = j_ >> 3, xj = j_ & 7;
                    const int rj = (ey ? (yj < 4 ? 1 : 2) : 0) * 3 + (ex ? (xj < 4 ? 1 : 2) : 0);
                    ci[r] += (ri != rj) ? -100.0f : 0.0f;
                }
            }
            sc[m] = MFMA(kf[m], qf[n], ci);
        }
        float sum = 0.f;
        #pragma unroll
        for (int m = 0; m < 4; ++m)
            #pragma unroll
            for (int r = 0; r < 4; ++r) {
                const float p = __expf(sc[m][r]);
                sc[m][r] = p; sum += p;
            }
        sum += __shfl_xor(sum, 16);
        sum += __shfl_xor(sum, 32);
        rinv[n] = 1.0f / sum;
        pf[0][n] = cat8(pk4(sc[0]), pk4(sc[1]));
        pf[1][n] = cat8(pk4(sc[2]), pk4(sc[3]));
    }

    // ---- O^T = V^T @ P^T; coalesced frag store ----
    f32x4 o0[2][4];
    #pragma unroll
    for (int o = 0; o < 2; ++o)
        #pragma unroll
        for (int n = 0; n < 4; ++n) o0[o][n] = FZ;
    #pragma unroll
    for (int kb = 0; kb < 2; ++kb)
        #pragma unroll
        for (int o = 0; o < 2; ++o)
            #pragma unroll
            for (int n = 0; n < 4; ++n)
                o0[o][n] = MFMA(vf[o][kb], pf[kb][n], o0[o][n]);

    bf16* const ob = obuf + (size_t)bid * 8192 + h * 2048;
    #pragma unroll
    for (int n = 0; n < 4; ++n)
        #pragma unroll
        for (int o = 0; o < 2; ++o)
            *(bf16x4*)(ob + (n*2 + o)*256 + lane*4) = pk4s(o0[o][n], rinv[n]);
}

// ---------------------------------------------------------------------------
// Projection by image rows (unchanged).
// ---------------------------------------------------------------------------
__global__ __launch_bounds__(512, 3)
void proj_rows(const bf16* __restrict__ obuf, const bf16* __restrict__ hprojf,
               const float* __restrict__ proj_b, float* __restrict__ out)
{
    __shared__ char sR[49152];   // [192 tok][256B bf16], col ^ SW(tok)
    const int tid  = threadIdx.x;
    const int lane = tid & 63;
    const int wv   = tid >> 6;
    const int lo   = lane & 15;
    const int hi   = lane >> 4;

    const int bid   = blockIdx.x;        // 1536 = 8 batch x 192 rows
    const int batch = bid & 7;
    const int hh    = bid >> 3;          // output row 0..191
    int hr = hh + 188; if (hr >= 192) hr -= 192;   // rolled-frame row
    const int wy = hr >> 3, iy = hr & 7;
    const int n_ = iy >> 1;

    #pragma unroll
    for (int k = 0; k < 6; ++k) {
        const int i  = tid + k*512;      // 0..3071
        const int wr = i >> 4;           // rolled-frame col
        const int cc = i & 15;           // 8-channel chunk
        const int wxx = wr >> 3, ix = wr & 7;
        const int win = (wy*NWX + wxx)*8 + batch;
        const int lo2 = (iy & 1)*8 + ix;
        const int hg = cc >> 2, oo = (cc >> 1) & 1, hp = cc & 1;
        const bf16* bp = obuf + (size_t)win*8192 + hg*2048 + (n_*2 + oo)*256;
        const bf16x4 p0 = *(const bf16x4*)(bp + ((hp*2    )*16 + lo2)*4);
        const bf16x4 p1 = *(const bf16x4*)(bp + ((hp*2 + 1)*16 + lo2)*4);
        int wo = wr + 4; if (wo >= 192) wo -= 192;
        *(bf16x8*)(sR + wo*256 + ((cc*16) ^ SW(wo))) = cat8(p0, p1);
    }
    __syncthreads();

    const int q  = wv >> 1;
    const int oh = wv & 1;
    const f32x4 FZ = {0.f, 0.f, 0.f, 0.f};
    f32x4 acc[4][3];
    #pragma unroll
    for (int tA = 0; tA < 4; ++tA)
        #pragma unroll
        for (int tN = 0; tN < 3; ++tN) acc[tA][tN] = FZ;

    #pragma unroll
    for (int kb = 0; kb < 4; ++kb) {
        bf16x8 of[3];
        #pragma unroll
        for (int tN = 0; tN < 3; ++tN) {
            const int tok = q*48 + tN*16 + lo;
            of[tN] = *(const bf16x8*)(sR + tok*256 + ((kb*64 + hi*16) ^ SW(tok)));
        }
        bf16x8 wf[4];
        #pragma unroll
        for (int tA = 0; tA < 4; ++tA)
            wf[tA] = *(const bf16x8*)(hprojf + (size_t)(((oh*4 + kb)*4 + tA)*64 + lane)*8);
        #pragma unroll
        for (int tA = 0; tA < 4; ++tA)
            #pragma unroll
            for (int tN = 0; tN < 3; ++tN)
                acc[tA][tN] = MFMA(of[tN], wf[tA], acc[tA][tN]);
    }

    #pragma unroll
    for (int tA = 0; tA < 4; ++tA) {
        const int oc = oh*64 + tA*16 + lo;
        const float pb = proj_b[oc];
        float* const orow = out + (size_t)(batch*128 + oc) * HWSZ + hh*HIMG;
        #pragma unroll
        for (int tN = 0; tN < 3; ++tN) {
            const int tb = q*48 + tN*16 + hi*4;
            float4 v;
            v.x = acc[tA][tN][0] + pb;
            v.y = acc[tA][tN][1] + pb;
            v.z = acc[tA][tN][2] + pb;
            v.w = acc[tA][tN][3] + pb;
            *(float4*)(orow + tb) = v;
        }
    }
}

// ---------------------------------------------------------------------------
// Fallback: fused one-wave-per-window kernel (round-6), for small workspaces.
// ---------------------------------------------------------------------------
template<int WSB>
__global__ __launch_bounds__(64, 2)
void swin_fused(const float* __restrict__ x, const float* __restrict__ qkv_w,
                const float* __restrict__ qkv_b, const float* __restrict__ proj_w,
                const float* __restrict__ proj_b, const float* __restrict__ rpb,
                const float* __restrict__ wb, const bf16* __restrict__ hqkv,
                const bf16* __restrict__ hproj, float* __restrict__ out)
{
    __shared__ char sX[16384];

    const int lane = threadIdx.x & 63;
    const int lo   = lane & 15;
    const int hi   = lane >> 4;

    const int bid   = blockIdx.x;
    const int batch = bid & 7;
    const int wrem  = bid >> 3;
    const int wy    = wrem / NWX;
    const int wx    = wrem - wy * NWX;
    const long xbase = (long)batch * 128 * HWSZ;

    const f32x4 FZ = {0.f, 0.f, 0.f, 0.f};
    const float SCALE = 0.17677669529663687f;
    const int prow = ((lo >> 2) << 3) + (lo & 3);

    {
        int hh = wy*8 + (lane >> 3) + 4; if (hh >= HIMG) hh -= HIMG;
        int ww = wx*8 + (lane & 7)  + 4; if (ww >= HIMG) ww -= HIMG;
        const float* xp = x + xbase + hh * HIMG + ww;
        char* const wp = sX + lane * 256;
        const int swz = SW(lane);
        #pragma unroll
        for (int g = 0; g < 16; ++g) {
            bf16x8 v;
            #pragma unroll
            for (int e = 0; e < 8; ++e) v[e] = (bf16)xp[(g*8 + e) * HWSZ];
            *(bf16x8*)(wp + ((16*g) ^ swz)) = v;
        }
    }

    const bool ey = (wy == 23), ex = (wx == 23);
    const bool edge = ey || ex;

    bf16x4 ob[4][2][4];

    #pragma unroll
    for (int h = 0; h < 4; ++h) {
        bf16x8 qf[4], kf[4];
        {
            f32x4 acc[2][4];
            #pragma unroll
            for (int a = 0; a < 2; ++a)
                #pragma unroll
                for (int n = 0; n < 4; ++n) acc[a][n] = FZ;
            #pragma unroll
            for (int kb = 0; kb < 4; ++kb) {
                bf16x8 xf[4];
                #pragma unroll
                for (int n = 0; n < 4; ++n) {
                    const int row = n*16 + lo;
                    xf[n] = *(const bf16x8*)(sX + row*256 + ((kb*64 + hi*16) ^ SW(row)));
                }
                const int coff = kb*32 + hi*8;
                const bf16x8 w0 = ldw<WSB>(qkv_w, hqkv, (h*32 + prow    ) * 128 + coff);
                const bf16x8 w1 = ldw<WSB>(qkv_w, hqkv, (h*32 + prow + 4) * 128 + coff);
                #pragma unroll
                for (int n = 0; n < 4; ++n) {
                    acc[0][n] = MFMA(w0, xf[n], acc[0][n]);
                    acc[1][n] = MFMA(w1, xf[n], acc[1][n]);
                }
            }
            const float4 b0 = *(const float4*)(qkv_b + h*32 + hi*8);
            const float4 b1 = *(const float4*)(qkv_b + h*32 + hi*8 + 4);
            #pragma unroll
            for (int n = 0; n < 4; ++n)
                qf[n] = cat8(pk4bs(acc[0][n], b0, SCALE), pk4bs(acc[1][n], b1, SCALE));
        }
        {
            f32x4 ak[2][4];
            #pragma unroll
            for (int a = 0; a < 2; ++a)
                #pragma unroll
                for (int m = 0; m < 4; ++m) ak[a][m] = FZ;
            #pragma unroll
            for (int kb = 0; kb < 4; ++kb) {
                bf16x8 xf[4];
                #pragma unroll
                for (int m = 0; m < 4; ++m) {
                    const int row = (m >> 1)*32 + (m & 1)*4 + prow;
                    xf[m] = *(const bf16x8*)(sX + row*256 + ((kb*64 + hi*16) ^ SW(row)));
                }
                const int coff = kb*32 + hi*8;
                const bf16x8 w0 = ldw<WSB>(qkv_w, hqkv, (128 + h*32 + prow    ) * 128 + coff);
                const bf16x8 w1 = ldw<WSB>(qkv_w, hqkv, (128 + h*32 + prow + 4) * 128 + coff);
                #pragma unroll
                for (int m = 0; m < 4; ++m) {
                    ak[0][m] = MFMA(w0, xf[m], ak[0][m]);
                    ak[1][m] = MFMA(w1, xf[m], ak[1][m]);
                }
            }
            const float4 b0 = *(const float4*)(qkv_b + 128 + h*32 + hi*8);
            const float4 b1 = *(const float4*)(qkv_b + 128 + h*32 + hi*8 + 4);
            #pragma unroll
            for (int m = 0; m < 4; ++m)
                kf[m] = cat8(pk4b(ak[0][m], b0), pk4b(ak[1][m], b1));
        }

        f32x4 s2[4][4];
        const float* wbh = wb + h * 4096;
        #pragma unroll
        for (int n = 0; n < 4; ++n) {
            const int i_ = n*16 + lo;
            const int yi = i_ >> 3, xi = i_ & 7;
            const int ri = (ey ? (yi < 4 ? 1 : 2) : 0) * 3 + (ex ? (xi < 4 ? 1 : 2) : 0);
            #pragma unroll
            for (int m = 0; m < 4; ++m) {
                const int j0 = (m >> 1)*32 + hi*8 + (m & 1)*4;
                f32x4 ci;
                if (WSB) ci = *(const f32x4*)(wbh + i_*64 + j0);
                else {
                    #pragma unroll
                    for (int r = 0; r < 4; ++r) {
                        const int j_ = j0 + r;
                        ci[r] = rpb[((yi - (j_ >> 3) + 7) * 15 + (xi - (j_ & 7) + 7)) * 4 + h];
                    }
                }
                if (edge) {
                    #pragma unroll
                    for (int r = 0; r < 4; ++r) {
                        const int j_ = j0 + r;
                        const int yj = j_ >> 3, xj = j_ & 7;
                        const int rj = (ey ? (yj < 4 ? 1 : 2) : 0) * 3 + (ex ? (xj < 4 ? 1 : 2) : 0);
                        ci[r] += (ri != rj) ? -100.0f : 0.0f;
                    }
                }
                s2[m][n] = MFMA(kf[m], qf[n], ci);
            }
        }
        float rinv[4];
        #pragma unroll
        for (int n = 0; n < 4; ++n) {
            float mx = -1e30f;
            #pragma unroll
            for (int m = 0; m < 4; ++m)
                #pragma unroll
                for (int r = 0; r < 4; ++r) mx = fmaxf(mx, s2[m][n][r]);
            mx = fmaxf(mx, __shfl_xor(mx, 16));
            mx = fmaxf(mx, __shfl_xor(mx, 32));
            float sum = 0.f;
            #pragma unroll
            for (int m = 0; m < 4; ++m)
                #pragma unroll
                for (int r = 0; r < 4; ++r) {
                    const float p = __expf(s2[m][n][r] - mx);
                    s2[m][n][r] = p; sum += p;
                }
            sum += __shfl_xor(sum, 16);
            sum += __shfl_xor(sum, 32);
            rinv[n] = 1.0f / sum;
        }
        bf16x8 pf[2][4];
        #pragma unroll
        for (int kb = 0; kb < 2; ++kb)
            #pragma unroll
            for (int n = 0; n < 4; ++n)
                pf[kb][n] = cat8(pk4(s2[kb*2][n]), pk4(s2[kb*2 + 1][n]));

        bf16x8 vf[2][2];
        {
            f32x4 av[4][2];
            #pragma unroll
            for (int m = 0; m < 4; ++m) { av[m][0] = FZ; av[m][1] = FZ; }
            #pragma unroll
            for (int kb = 0; kb < 4; ++kb) {
                bf16x8 xv[4];
                #pragma unroll
                for (int m = 0; m < 4; ++m) {
                    const int row = (m >> 1)*32 + (m & 1)*4 + prow;
                    xv[m] = *(const bf16x8*)(sX + row*256 + ((kb*64 + hi*16) ^ SW(row)));
                }
                const int coff = kb*32 + hi*8;
                const bf16x8 w0 = ldw<WSB>(qkv_w, hqkv, (256 + h*32 + lo)      * 128 + coff);
                const bf16x8 w1 = ldw<WSB>(qkv_w, hqkv, (256 + h*32 + 16 + lo) * 128 + coff);
                #pragma unroll
                for (int m = 0; m < 4; ++m) {
                    av[m][0] = MFMA(xv[m], w0, av[m][0]);
                    av[m][1] = MFMA(xv[m], w1, av[m][1]);
                }
            }
            const float bv0 = qkv_b[256 + h*32 + lo];
            const float bv1 = qkv_b[256 + h*32 + 16 + lo];
            #pragma unroll
            for (int kb = 0; kb < 2; ++kb) {
                vf[0][kb] = cat8(pk4c(av[kb*2][0], bv0), pk4c(av[kb*2 + 1][0], bv0));
                vf[1][kb] = cat8(pk4c(av[kb*2][1], bv1), pk4c(av[kb*2 + 1][1], bv1));
            }
        }
        {
            f32x4 o0[2][4];
            #pragma unroll
            for (int o = 0; o < 2; ++o)
                #pragma unroll
                for (int n = 0; n < 4; ++n) o0[o][n] = FZ;
            #pragma unroll
            for (int kb = 0; kb < 2; ++kb)
                #pragma unroll
                for (int o = 0; o < 2; ++o)
                    #pragma unroll
                    for (int n = 0; n < 4; ++n)
                        o0[o][n] = MFMA(vf[o][kb], pf[kb][n], o0[o][n]);
            #pragma unroll
            for (int o = 0; o < 2; ++o)
                #pragma unroll
                for (int n = 0; n < 4; ++n)
                    ob[h][o][n] = pk4s(o0[o][n], rinv[n]);
        }
    }

    #pragma unroll
    for (int h = 0; h < 4; ++h)
        #pragma unroll
        for (int o = 0; o < 2; ++o) {
            const int cb = h*64 + o*32 + hi*8;
            #pragma unroll
            for (int n = 0; n < 4; ++n) {
                const int t = n*16 + lo;
                *(bf16x4*)(sX + t*256 + (cb ^ SW(t))) = ob[h][o][n];
            }
        }

    #pragma unroll
    for (int c4 = 0; c4 < 4; ++c4) {
        f32x4 pr[2][4];
        #pragma unroll
        for (int a = 0; a < 2; ++a)
            #pragma unroll
            for (int n = 0; n < 4; ++n) pr[a][n] = FZ;
        #pragma unroll
        for (int kb = 0; kb < 4; ++kb) {
            bf16x8 af[4];
            #pragma unroll
            for (int n = 0; n < 4; ++n) {
                const int row = n*16 + lo;
                af[n] = *(const bf16x8*)(sX + row*256 + ((kb*64 + hi*16) ^ SW(row)));
            }
            const int coff = kb*32 + hi*8;
            const bf16x8 w0 = ldw<WSB>(proj_w, hproj, (c4*32 + lo)      * 128 + coff);
            const bf16x8 w1 = ldw<WSB>(proj_w, hproj, (c4*32 + 16 + lo) * 128 + coff);
            #pragma unroll
            for (int n = 0; n < 4; ++n) {
                pr[0][n] = MFMA(w0, af[n], pr[0][n]);
                pr[1][n] = MFMA(w1, af[n], pr[1][n]);
            }
        }
        #pragma unroll
        for (int a = 0; a < 2; ++a) {
            const int ocb = c4*32 + a*16 + hi*4;
            const float4 pb = *(const float4*)(proj_b + ocb);
            #pragma unroll
            for (int n = 0; n < 4; ++n) {
                const int t = n*16 + lo;
                int hh = wy*8 + (t >> 3) + 4; if (hh >= HIMG) hh -= HIMG;
                int ww = wx*8 + (t & 7)  + 4; if (ww >= HIMG) ww -= HIMG;
                float* op = out + (long)(batch*128 + ocb) * HWSZ + hh*HIMG + ww;
                op[0]      = pr[a][n][0] + pb.x;
                op[HWSZ]   = pr[a][n][1] + pb.y;
                op[2*HWSZ] = pr[a][n][2] + pb.z;
                op[3*HWSZ] = pr[a][n][3] + pb.w;
            }
        }
    }
}

extern "C" void kernel_launch(void* const* d_in, const int* in_sizes, int n_in,
                              void* d_out, int out_size, void* d_ws, size_t ws_size,
                              hipStream_t stream) {
    const float* x      = (const float*)d_in[0];
    const float* qkv_w  = (const float*)d_in[1];
    const float* qkv_b  = (const float*)d_in[2];
    const float* proj_w = (const float*)d_in[3];
    const float* proj_b = (const float*)d_in[4];
    const float* rpb    = (const float*)d_in[5];
    float* out = (float*)d_out;

    // ws bytes: [0,64K) wbias f32 | [64K,160K) hqkv | [160K,192K) hproj
    //           [192K,256K) wbf f32 | [256K,352K) hqkvf | [352K,384K) hprojf
    //           [384K, +75.5M) obuf
    const size_t SETUP = 393216;
    const size_t OSZ   = (size_t)4608 * 16384;

    float* wbias = (float*)d_ws;
    bf16*  hqkv  = (bf16*)((char*)d_ws + 65536);
    bf16*  hproj = (bf16*)((char*)d_ws + 163840);
    float* wbf   = (float*)((char*)d_ws + 196608);
    bf16*  hqkvf = (bf16*)((char*)d_ws + 262144);
    bf16*  hprojf= (bf16*)((char*)d_ws + 360448);
    bf16*  obuf  = (bf16*)((char*)d_ws + SETUP);

    if (ws_size >= SETUP + OSZ) {
        setup_ws<<<640, 256, 0, stream>>>(rpb, qkv_w, proj_w, wbias, hqkv, hproj,
                                          wbf, hqkvf, hprojf);
        qkv_attn<<<4608, 256, 0, stream>>>(x, qkv_b, hqkvf, wbf, obuf);
        proj_rows<<<1536, 512, 0, stream>>>(obuf, hprojf, proj_b, out);
    } else if (ws_size >= SETUP) {
        setup_ws<<<640, 256, 0, stream>>>(rpb, qkv_w, proj_w, wbias, hqkv, hproj,
                                          wbf, hqkvf, hprojf);
        swin_fused<1><<<4608, 64, 0, stream>>>(x, qkv_w, qkv_b, proj_w, proj_b, rpb,
                                               wbias, hqkv, hproj, out);
    } else {
        swin_fused<0><<<4608, 64, 0, stream>>>(x, qkv_w, qkv_b, proj_w, proj_b, rpb,
                                               nullptr, nullptr, nullptr, out);
    }
}

// Round 16
// 150.285 us; speedup vs baseline: 2.1795x; 1.4284x over previous
//
#include <hip/hip_runtime.h>

#define HIMG 192
#define HWSZ (192*192)
#define NWX  24

typedef __bf16 bf16;
typedef __bf16 bf16x2 __attribute__((ext_vector_type(2)));
typedef __bf16 bf16x4 __attribute__((ext_vector_type(4)));
typedef __bf16 bf16x8 __attribute__((ext_vector_type(8)));
typedef float  f32x4  __attribute__((ext_vector_type(4)));

#define MFMA(a,b,c) __builtin_amdgcn_mfma_f32_16x16x32_bf16((a),(b),(c),0,0,0)
#define SW(r) (((((r)&7) ^ ((((r)>>3)&1)<<2))) << 4)

static __device__ __forceinline__ bf16x8 ldg8(const float* p) {
    const float4 u = ((const float4*)p)[0];
    const float4 v = ((const float4*)p)[1];
    bf16x8 r;
    r[0]=(bf16)u.x; r[1]=(bf16)u.y; r[2]=(bf16)u.z; r[3]=(bf16)u.w;
    r[4]=(bf16)v.x; r[5]=(bf16)v.y; r[6]=(bf16)v.z; r[7]=(bf16)v.w;
    return r;
}
template<int WSB>
static __device__ __forceinline__ bf16x8 ldw(const float* wf, const bf16* wh, int off) {
    if (WSB) return *(const bf16x8*)(wh + off);
    return ldg8(wf + off);
}
static __device__ __forceinline__ bf16x4 pk4b(f32x4 v, float4 b) {
    bf16x4 r; r[0]=(bf16)(v[0]+b.x); r[1]=(bf16)(v[1]+b.y);
    r[2]=(bf16)(v[2]+b.z); r[3]=(bf16)(v[3]+b.w); return r;
}
static __device__ __forceinline__ bf16x4 pk4bs(f32x4 v, float4 b, float s) {
    bf16x4 r; r[0]=(bf16)((v[0]+b.x)*s); r[1]=(bf16)((v[1]+b.y)*s);
    r[2]=(bf16)((v[2]+b.z)*s); r[3]=(bf16)((v[3]+b.w)*s); return r;
}
static __device__ __forceinline__ bf16x4 pk4c(f32x4 v, float b) {
    bf16x4 r; r[0]=(bf16)(v[0]+b); r[1]=(bf16)(v[1]+b);
    r[2]=(bf16)(v[2]+b); r[3]=(bf16)(v[3]+b); return r;
}
static __device__ __forceinline__ bf16x4 pk4s(f32x4 v, float s) {
    bf16x4 r; r[0]=(bf16)(v[0]*s); r[1]=(bf16)(v[1]*s);
    r[2]=(bf16)(v[2]*s); r[3]=(bf16)(v[3]*s); return r;
}
static __device__ __forceinline__ bf16x4 pk4(f32x4 v) {
    bf16x4 r; r[0]=(bf16)v[0]; r[1]=(bf16)v[1]; r[2]=(bf16)v[2]; r[3]=(bf16)v[3]; return r;
}
static __device__ __forceinline__ bf16x8 cat8(bf16x4 a, bf16x4 b) {
    bf16x8 r; r[0]=a[0]; r[1]=a[1]; r[2]=a[2]; r[3]=a[3];
    r[4]=b[0]; r[5]=b[1]; r[6]=b[2]; r[7]=b[3]; return r;
}
static __device__ __forceinline__ f32x4 splat4(float b) {
    f32x4 r; r[0]=b; r[1]=b; r[2]=b; r[3]=b; return r;
}
static __device__ __forceinline__ f32x4 f4of(float4 b) {
    f32x4 r; r[0]=b.x; r[1]=b.y; r[2]=b.z; r[3]=b.w; return r;
}
static __device__ __forceinline__ f32x4 f4ofs(float4 b, float s) {
    f32x4 r; r[0]=b.x*s; r[1]=b.y*s; r[2]=b.z*s; r[3]=b.w*s; return r;
}

// ---------------------------------------------------------------------------
// Setup: parameter tables incl. frag-layout (lane-coalesced) copies.
// hqkvf Q-section is pre-scaled by 32^-0.5.
// ---------------------------------------------------------------------------
__global__ __launch_bounds__(256) void setup_ws(const float* __restrict__ rpb,
                                                const float* __restrict__ qkv_w,
                                                const float* __restrict__ proj_w,
                                                float* __restrict__ wbias,
                                                bf16* __restrict__ hqkv,
                                                bf16* __restrict__ hproj,
                                                float* __restrict__ wbf,
                                                bf16* __restrict__ hqkvf,
                                                bf16* __restrict__ hprojf) {
    const int e = blockIdx.x * 256 + threadIdx.x;   // 0..163839
    if (e < 16384) {
        const int h = e >> 12, i = (e >> 6) & 63, j = e & 63;
        const int dy = (i >> 3) - (j >> 3) + 7;
        const int dx = (i & 7)  - (j & 7)  + 7;
        wbias[e] = rpb[(dy * 15 + dx) * 4 + h];
    } else if (e < 65536) {
        const int i = e - 16384;
        hqkv[i] = (bf16)qkv_w[i];
    } else if (e < 81920) {
        const int i = e - 65536;
        hproj[i] = (bf16)proj_w[i];
    } else if (e < 98304) {
        const int t = e - 81920;
        const int r = t & 3, lane = (t >> 2) & 63;
        const int m = (t >> 8) & 3, n = (t >> 10) & 3, h = t >> 12;
        const int lo = lane & 15, hi = lane >> 4;
        const int i_ = n*16 + lo;
        const int j_ = (m >> 1)*32 + hi*8 + (m & 1)*4 + r;
        const int dy = (i_ >> 3) - (j_ >> 3) + 7;
        const int dx = (i_ & 7)  - (j_ & 7)  + 7;
        wbf[t] = rpb[(dy * 15 + dx) * 4 + h];
    } else if (e < 147456) {
        const int t = e - 98304;
        const int el = t & 7, lane = (t >> 3) & 63;
        const int a = (t >> 9) & 1, kb = (t >> 10) & 3;
        const int h = (t >> 12) & 3, ph = t >> 14;
        const int lo = lane & 15, hi = lane >> 4;
        const int prow = ((lo >> 2) << 3) + (lo & 3);
        const int row = (ph == 2) ? (256 + h*32 + a*16 + lo)
                                  : (ph*128 + h*32 + prow + a*4);
        const int col = kb*32 + hi*8 + el;
        float wv_ = qkv_w[row*128 + col];
        if (ph == 0) wv_ *= 0.17677669529663687f;   // fold attention scale into Wq
        hqkvf[t] = (bf16)wv_;
    } else {
        const int t = e - 147456;
        const int el = t & 7, lane = (t >> 3) & 63;
        const int tA = (t >> 9) & 3, kb = (t >> 11) & 3, oh = t >> 13;
        const int lo = lane & 15, hi = lane >> 4;
        const int row = oh*64 + tA*16 + lo;
        const int col = kb*32 + hi*8 + el;
        hprojf[t] = (bf16)proj_w[row*128 + col];
    }
}

// ---------------------------------------------------------------------------
// Fused gather + QKV + attention. 256 thr = 4 waves = 4 heads, one barrier.
// __launch_bounds__(256,3): ONLY safe occupancy bound (any cap<=128 spills —
// verified rounds 14/15). Gather: float4 loads (roll-aligned), quad-channel
// bf16x4 LDS writes (halved bank conflicts vs pair-channel).
// Trims: biases as MFMA C-init, SCALE folded into Wq, no-max-sub softmax.
// ---------------------------------------------------------------------------
__global__ __launch_bounds__(256, 3)
void qkv_attn(const float* __restrict__ x, const float* __restrict__ qkv_b,
              const bf16* __restrict__ hqkvf, const float* __restrict__ wbf,
              bf16* __restrict__ obuf)
{
    __shared__ char sX[16384];   // [64 tok][256B ch] bf16, col ^ SW(tok)
    const int tid  = threadIdx.x;
    const int lane = tid & 63;
    const int h    = tid >> 6;
    const int lo   = lane & 15;
    const int hi   = lane >> 4;

    const int bid   = blockIdx.x;        // == win index
    const int batch = bid & 7;
    const int wrem  = bid >> 3;
    const int wy    = wrem / NWX;
    const int wx    = wrem - wy * NWX;

    const f32x4 FZ = {0.f, 0.f, 0.f, 0.f};
    const float SCALE = 0.17677669529663687f;
    const int prow = ((lo >> 2) << 3) + (lo & 3);

    // ---- gather+roll -> LDS: 512 (chq,row,w4) tiles, 4 planes per tile ----
    {
        const int hbase = wy*8 + 4;
        const int wbase = wx*8 + 4;
        #pragma unroll
        for (int k = 0; k < 2; ++k) {
            const int id  = k*256 + tid;     // 0..511
            const int w4  = id & 1;
            const int row = (id >> 1) & 7;
            const int chq = id >> 4;         // channel quad 0..31
            int hh = hbase + row;  if (hh >= HIMG) hh -= HIMG;
            int ww = wbase + w4*4; if (ww >= HIMG) ww -= HIMG;
            const float* p0 = x + (size_t)(batch*128 + chq*4) * HWSZ + hh*HIMG + ww;
            const float4 a = *(const float4*)p0;
            const float4 b = *(const float4*)(p0 + HWSZ);
            const float4 c = *(const float4*)(p0 + 2*HWSZ);
            const float4 d = *(const float4*)(p0 + 3*HWSZ);
            const int t0 = row*8 + w4*4;
            #pragma unroll
            for (int e = 0; e < 4; ++e) {
                const int t = t0 + e;
                bf16x4 pr;
                pr[0] = (bf16)(&a.x)[e]; pr[1] = (bf16)(&b.x)[e];
                pr[2] = (bf16)(&c.x)[e]; pr[3] = (bf16)(&d.x)[e];
                *(bf16x4*)(sX + t*256 + ((8*chq) ^ SW(t))) = pr;
            }
        }
    }
    __syncthreads();   // only barrier

    const bf16* const wQ = hqkvf + h * 4096;            // pre-scaled
    const bf16* const wK = hqkvf + 16384 + h * 4096;
    const bf16* const wV = hqkvf + 32768 + h * 4096;

    bf16x8 qf[4], kf[4], vf[2][2];

    // ---- Q^T = (S*Wq) @ X^T, bias via C-init ----
    {
        const float4 b0 = *(const float4*)(qkv_b + h*32 + hi*8);
        const float4 b1 = *(const float4*)(qkv_b + h*32 + hi*8 + 4);
        const f32x4 c0 = f4ofs(b0, SCALE);
        const f32x4 c1 = f4ofs(b1, SCALE);
        f32x4 acc[2][4];
        #pragma unroll
        for (int n = 0; n < 4; ++n) { acc[0][n] = c0; acc[1][n] = c1; }
        #pragma unroll
        for (int kb = 0; kb < 4; ++kb) {
            bf16x8 xf[4];
            #pragma unroll
            for (int n = 0; n < 4; ++n) {
                const int row = n*16 + lo;
                xf[n] = *(const bf16x8*)(sX + row*256 + ((kb*64 + hi*16) ^ SW(row)));
            }
            const bf16x8 w0 = *(const bf16x8*)(wQ + (kb*2    )*512 + lane*8);
            const bf16x8 w1 = *(const bf16x8*)(wQ + (kb*2 + 1)*512 + lane*8);
            #pragma unroll
            for (int n = 0; n < 4; ++n) {
                acc[0][n] = MFMA(w0, xf[n], acc[0][n]);
                acc[1][n] = MFMA(w1, xf[n], acc[1][n]);
            }
        }
        #pragma unroll
        for (int n = 0; n < 4; ++n)
            qf[n] = cat8(pk4(acc[0][n]), pk4(acc[1][n]));
    }

    // ---- K^T and V merged (shared permuted-row X frags), bias via C-init ----
    {
        const float4 k0 = *(const float4*)(qkv_b + 128 + h*32 + hi*8);
        const float4 k1 = *(const float4*)(qkv_b + 128 + h*32 + hi*8 + 4);
        const float bv0 = qkv_b[256 + h*32 + lo];
        const float bv1 = qkv_b[256 + h*32 + 16 + lo];
        const f32x4 ck0 = f4of(k0), ck1 = f4of(k1);
        const f32x4 cv0 = splat4(bv0), cv1 = splat4(bv1);
        f32x4 ak[2][4], av[4][2];
        #pragma unroll
        for (int m = 0; m < 4; ++m) {
            ak[0][m] = ck0; ak[1][m] = ck1; av[m][0] = cv0; av[m][1] = cv1;
        }
        #pragma unroll
        for (int kb = 0; kb < 4; ++kb) {
            bf16x8 xf[4];
            #pragma unroll
            for (int m = 0; m < 4; ++m) {
                const int row = (m >> 1)*32 + (m & 1)*4 + prow;
                xf[m] = *(const bf16x8*)(sX + row*256 + ((kb*64 + hi*16) ^ SW(row)));
            }
            const bf16x8 wk0 = *(const bf16x8*)(wK + (kb*2    )*512 + lane*8);
            const bf16x8 wk1 = *(const bf16x8*)(wK + (kb*2 + 1)*512 + lane*8);
            const bf16x8 wv0 = *(const bf16x8*)(wV + (kb*2    )*512 + lane*8);
            const bf16x8 wv1 = *(const bf16x8*)(wV + (kb*2 + 1)*512 + lane*8);
            #pragma unroll
            for (int m = 0; m < 4; ++m) {
                ak[0][m] = MFMA(wk0, xf[m], ak[0][m]);
                ak[1][m] = MFMA(wk1, xf[m], ak[1][m]);
                av[m][0] = MFMA(xf[m], wv0, av[m][0]);
                av[m][1] = MFMA(xf[m], wv1, av[m][1]);
            }
        }
        #pragma unroll
        for (int m = 0; m < 4; ++m)
            kf[m] = cat8(pk4(ak[0][m]), pk4(ak[1][m]));
        #pragma unroll
        for (int kb = 0; kb < 2; ++kb) {
            vf[0][kb] = cat8(pk4(av[kb*2][0]), pk4(av[kb*2 + 1][0]));
            vf[1][kb] = cat8(pk4(av[kb*2][1]), pk4(av[kb*2 + 1][1]));
        }
    }

    // ---- S^T = K @ Q^T + (bias+mask as C-init); softmax (no max-sub) ----
    const bool ey = (wy == 23), ex = (wx == 23);
    const bool edge = ey || ex;
    const float* const wbh = wbf + h * 4096;
    bf16x8 pf[2][4];
    float rinv[4];
    #pragma unroll
    for (int n = 0; n < 4; ++n) {
        const int i_ = n*16 + lo;
        const int yi = i_ >> 3, xi = i_ & 7;
        const int ri = (ey ? (yi < 4 ? 1 : 2) : 0) * 3 + (ex ? (xi < 4 ? 1 : 2) : 0);
        f32x4 sc[4];
        #pragma unroll
        for (int m = 0; m < 4; ++m) {
            f32x4 ci = *(const f32x4*)(wbh + (n*4 + m)*256 + lane*4);
            if (edge) {
                #pragma unroll
                for (int r = 0; r < 4; ++r) {
                    const int j_ = (m >> 1)*32 + hi*8 + (m & 1)*4 + r;
                    const int yj = j_ >> 3, xj = j_ & 7;
                    const int rj = (ey ? (yj < 4 ? 1 : 2) : 0) * 3 + (ex ? (xj < 4 ? 1 : 2) : 0);
                    ci[r] += (ri != rj) ? -100.0f : 0.0f;
                }
            }
            sc[m] = MFMA(kf[m], qf[n], ci);
        }
        float sum = 0.f;
        #pragma unroll
        for (int m = 0; m < 4; ++m)
            #pragma unroll
            for (int r = 0; r < 4; ++r) {
                const float p = __expf(sc[m][r]);
                sc[m][r] = p; sum += p;
            }
        sum += __shfl_xor(sum, 16);
        sum += __shfl_xor(sum, 32);
        rinv[n] = 1.0f / sum;
        pf[0][n] = cat8(pk4(sc[0]), pk4(sc[1]));
        pf[1][n] = cat8(pk4(sc[2]), pk4(sc[3]));
    }

    // ---- O^T = V^T @ P^T; coalesced frag store ----
    f32x4 o0[2][4];
    #pragma unroll
    for (int o = 0; o < 2; ++o)
        #pragma unroll
        for (int n = 0; n < 4; ++n) o0[o][n] = FZ;
    #pragma unroll
    for (int kb = 0; kb < 2; ++kb)
        #pragma unroll
        for (int o = 0; o < 2; ++o)
            #pragma unroll
            for (int n = 0; n < 4; ++n)
                o0[o][n] = MFMA(vf[o][kb], pf[kb][n], o0[o][n]);

    bf16* const ob = obuf + (size_t)bid * 8192 + h * 2048;
    #pragma unroll
    for (int n = 0; n < 4; ++n)
        #pragma unroll
        for (int o = 0; o < 2; ++o)
            *(bf16x4*)(ob + (n*2 + o)*256 + lane*4) = pk4s(o0[o][n], rinv[n]);
}

// ---------------------------------------------------------------------------
// Projection by image rows (unchanged).
// ---------------------------------------------------------------------------
__global__ __launch_bounds__(512, 3)
void proj_rows(const bf16* __restrict__ obuf, const bf16* __restrict__ hprojf,
               const float* __restrict__ proj_b, float* __restrict__ out)
{
    __shared__ char sR[49152];   // [192 tok][256B bf16], col ^ SW(tok)
    const int tid  = threadIdx.x;
    const int lane = tid & 63;
    const int wv   = tid >> 6;
    const int lo   = lane & 15;
    const int hi   = lane >> 4;

    const int bid   = blockIdx.x;        // 1536 = 8 batch x 192 rows
    const int batch = bid & 7;
    const int hh    = bid >> 3;          // output row 0..191
    int hr = hh + 188; if (hr >= 192) hr -= 192;   // rolled-frame row
    const int wy = hr >> 3, iy = hr & 7;
    const int n_ = iy >> 1;

    #pragma unroll
    for (int k = 0; k < 6; ++k) {
        const int i  = tid + k*512;      // 0..3071
        const int wr = i >> 4;           // rolled-frame col
        const int cc = i & 15;           // 8-channel chunk
        const int wxx = wr >> 3, ix = wr & 7;
        const int win = (wy*NWX + wxx)*8 + batch;
        const int lo2 = (iy & 1)*8 + ix;
        const int hg = cc >> 2, oo = (cc >> 1) & 1, hp = cc & 1;
        const bf16* bp = obuf + (size_t)win*8192 + hg*2048 + (n_*2 + oo)*256;
        const bf16x4 p0 = *(const bf16x4*)(bp + ((hp*2    )*16 + lo2)*4);
        const bf16x4 p1 = *(const bf16x4*)(bp + ((hp*2 + 1)*16 + lo2)*4);
        int wo = wr + 4; if (wo >= 192) wo -= 192;
        *(bf16x8*)(sR + wo*256 + ((cc*16) ^ SW(wo))) = cat8(p0, p1);
    }
    __syncthreads();

    const int q  = wv >> 1;
    const int oh = wv & 1;
    const f32x4 FZ = {0.f, 0.f, 0.f, 0.f};
    f32x4 acc[4][3];
    #pragma unroll
    for (int tA = 0; tA < 4; ++tA)
        #pragma unroll
        for (int tN = 0; tN < 3; ++tN) acc[tA][tN] = FZ;

    #pragma unroll
    for (int kb = 0; kb < 4; ++kb) {
        bf16x8 of[3];
        #pragma unroll
        for (int tN = 0; tN < 3; ++tN) {
            const int tok = q*48 + tN*16 + lo;
            of[tN] = *(const bf16x8*)(sR + tok*256 + ((kb*64 + hi*16) ^ SW(tok)));
        }
        bf16x8 wf[4];
        #pragma unroll
        for (int tA = 0; tA < 4; ++tA)
            wf[tA] = *(const bf16x8*)(hprojf + (size_t)(((oh*4 + kb)*4 + tA)*64 + lane)*8);
        #pragma unroll
        for (int tA = 0; tA < 4; ++tA)
            #pragma unroll
            for (int tN = 0; tN < 3; ++tN)
                acc[tA][tN] = MFMA(of[tN], wf[tA], acc[tA][tN]);
    }

    #pragma unroll
    for (int tA = 0; tA < 4; ++tA) {
        const int oc = oh*64 + tA*16 + lo;
        const float pb = proj_b[oc];
        float* const orow = out + (size_t)(batch*128 + oc) * HWSZ + hh*HIMG;
        #pragma unroll
        for (int tN = 0; tN < 3; ++tN) {
            const int tb = q*48 + tN*16 + hi*4;
            float4 v;
            v.x = acc[tA][tN][0] + pb;
            v.y = acc[tA][tN][1] + pb;
            v.z = acc[tA][tN][2] + pb;
            v.w = acc[tA][tN][3] + pb;
            *(float4*)(orow + tb) = v;
        }
    }
}

// ---------------------------------------------------------------------------
// Fallback: fused one-wave-per-window kernel (round-6), for small workspaces.
// ---------------------------------------------------------------------------
template<int WSB>
__global__ __launch_bounds__(64, 2)
void swin_fused(const float* __restrict__ x, const float* __restrict__ qkv_w,
                const float* __restrict__ qkv_b, const float* __restrict__ proj_w,
                const float* __restrict__ proj_b, const float* __restrict__ rpb,
                const float* __restrict__ wb, const bf16* __restrict__ hqkv,
                const bf16* __restrict__ hproj, float* __restrict__ out)
{
    __shared__ char sX[16384];

    const int lane = threadIdx.x & 63;
    const int lo   = lane & 15;
    const int hi   = lane >> 4;

    const int bid   = blockIdx.x;
    const int batch = bid & 7;
    const int wrem  = bid >> 3;
    const int wy    = wrem / NWX;
    const int wx    = wrem - wy * NWX;
    const long xbase = (long)batch * 128 * HWSZ;

    const f32x4 FZ = {0.f, 0.f, 0.f, 0.f};
    const float SCALE = 0.17677669529663687f;
    const int prow = ((lo >> 2) << 3) + (lo & 3);

    {
        int hh = wy*8 + (lane >> 3) + 4; if (hh >= HIMG) hh -= HIMG;
        int ww = wx*8 + (lane & 7)  + 4; if (ww >= HIMG) ww -= HIMG;
        const float* xp = x + xbase + hh * HIMG + ww;
        char* const wp = sX + lane * 256;
        const int swz = SW(lane);
        #pragma unroll
        for (int g = 0; g < 16; ++g) {
            bf16x8 v;
            #pragma unroll
            for (int e = 0; e < 8; ++e) v[e] = (bf16)xp[(g*8 + e) * HWSZ];
            *(bf16x8*)(wp + ((16*g) ^ swz)) = v;
        }
    }

    const bool ey = (wy == 23), ex = (wx == 23);
    const bool edge = ey || ex;

    bf16x4 ob[4][2][4];

    #pragma unroll
    for (int h = 0; h < 4; ++h) {
        bf16x8 qf[4], kf[4];
        {
            f32x4 acc[2][4];
            #pragma unroll
            for (int a = 0; a < 2; ++a)
                #pragma unroll
                for (int n = 0; n < 4; ++n) acc[a][n] = FZ;
            #pragma unroll
            for (int kb = 0; kb < 4; ++kb) {
                bf16x8 xf[4];
                #pragma unroll
                for (int n = 0; n < 4; ++n) {
                    const int row = n*16 + lo;
                    xf[n] = *(const bf16x8*)(sX + row*256 + ((kb*64 + hi*16) ^ SW(row)));
                }
                const int coff = kb*32 + hi*8;
                const bf16x8 w0 = ldw<WSB>(qkv_w, hqkv, (h*32 + prow    ) * 128 + coff);
                const bf16x8 w1 = ldw<WSB>(qkv_w, hqkv, (h*32 + prow + 4) * 128 + coff);
                #pragma unroll
                for (int n = 0; n < 4; ++n) {
                    acc[0][n] = MFMA(w0, xf[n], acc[0][n]);
                    acc[1][n] = MFMA(w1, xf[n], acc[1][n]);
                }
            }
            const float4 b0 = *(const float4*)(qkv_b + h*32 + hi*8);
            const float4 b1 = *(const float4*)(qkv_b + h*32 + hi*8 + 4);
            #pragma unroll
            for (int n = 0; n < 4; ++n)
                qf[n] = cat8(pk4bs(acc[0][n], b0, SCALE), pk4bs(acc[1][n], b1, SCALE));
        }
        {
            f32x4 ak[2][4];
            #pragma unroll
            for (int a = 0; a < 2; ++a)
                #pragma unroll
                for (int m = 0; m < 4; ++m) ak[a][m] = FZ;
            #pragma unroll
            for (int kb = 0; kb < 4; ++kb) {
                bf16x8 xf[4];
                #pragma unroll
                for (int m = 0; m < 4; ++m) {
                    const int row = (m >> 1)*32 + (m & 1)*4 + prow;
                    xf[m] = *(const bf16x8*)(sX + row*256 + ((kb*64 + hi*16) ^ SW(row)));
                }
                const int coff = kb*32 + hi*8;
                const bf16x8 w0 = ldw<WSB>(qkv_w, hqkv, (128 + h*32 + prow    ) * 128 + coff);
                const bf16x8 w1 = ldw<WSB>(qkv_w, hqkv, (128 + h*32 + prow + 4) * 128 + coff);
                #pragma unroll
                for (int m = 0; m < 4; ++m) {
                    ak[0][m] = MFMA(w0, xf[m], ak[0][m]);
                    ak[1][m] = MFMA(w1, xf[m], ak[1][m]);
                }
            }
            const float4 b0 = *(const float4*)(qkv_b + 128 + h*32 + hi*8);
            const float4 b1 = *(const float4*)(qkv_b + 128 + h*32 + hi*8 + 4);
            #pragma unroll
            for (int m = 0; m < 4; ++m)
                kf[m] = cat8(pk4b(ak[0][m], b0), pk4b(ak[1][m], b1));
        }

        f32x4 s2[4][4];
        const float* wbh = wb + h * 4096;
        #pragma unroll
        for (int n = 0; n < 4; ++n) {
            const int i_ = n*16 + lo;
            const int yi = i_ >> 3, xi = i_ & 7;
            const int ri = (ey ? (yi < 4 ? 1 : 2) : 0) * 3 + (ex ? (xi < 4 ? 1 : 2) : 0);
            #pragma unroll
            for (int m = 0; m < 4; ++m) {
                const int j0 = (m >> 1)*32 + hi*8 + (m & 1)*4;
                f32x4 ci;
                if (WSB) ci = *(const f32x4*)(wbh + i_*64 + j0);
                else {
                    #pragma unroll
                    for (int r = 0; r < 4; ++r) {
                        const int j_ = j0 + r;
                        ci[r] = rpb[((yi - (j_ >> 3) + 7) * 15 + (xi - (j_ & 7) + 7)) * 4 + h];
                    }
                }
                if (edge) {
                    #pragma unroll
                    for (int r = 0; r < 4; ++r) {
                        const int j_ = j0 + r;
                        const int yj = j_ >> 3, xj = j_ & 7;
                        const int rj = (ey ? (yj < 4 ? 1 : 2) : 0) * 3 + (ex ? (xj < 4 ? 1 : 2) : 0);
                        ci[r] += (ri != rj) ? -100.0f : 0.0f;
                    }
                }
                s2[m][n] = MFMA(kf[m], qf[n], ci);
            }
        }
        float rinv[4];
        #pragma unroll
        for (int n = 0; n < 4; ++n) {
            float mx = -1e30f;
            #pragma unroll
            for (int m = 0; m < 4; ++m)
                #pragma unroll
                for (int r = 0; r < 4; ++r) mx = fmaxf(mx, s2[m][n][r]);
            mx = fmaxf(mx, __shfl_xor(mx, 16));
            mx = fmaxf(mx, __shfl_xor(mx, 32));
            float sum = 0.f;
            #pragma unroll
            for (int m = 0; m < 4; ++m)
                #pragma unroll
                for (int r = 0; r < 4; ++r) {
                    const float p = __expf(s2[m][n][r] - mx);
                    s2[m][n][r] = p; sum += p;
                }
            sum += __shfl_xor(sum, 16);
            sum += __shfl_xor(sum, 32);
            rinv[n] = 1.0f / sum;
        }
        bf16x8 pf[2][4];
        #pragma unroll
        for (int kb = 0; kb < 2; ++kb)
            #pragma unroll
            for (int n = 0; n < 4; ++n)
                pf[kb][n] = cat8(pk4(s2[kb*2][n]), pk4(s2[kb*2 + 1][n]));

        bf16x8 vf[2][2];
        {
            f32x4 av[4][2];
            #pragma unroll
            for (int m = 0; m < 4; ++m) { av[m][0] = FZ; av[m][1] = FZ; }
            #pragma unroll
            for (int kb = 0; kb < 4; ++kb) {
                bf16x8 xv[4];
                #pragma unroll
                for (int m = 0; m < 4; ++m) {
                    const int row = (m >> 1)*32 + (m & 1)*4 + prow;
                    xv[m] = *(const bf16x8*)(sX + row*256 + ((kb*64 + hi*16) ^ SW(row)));
                }
                const int coff = kb*32 + hi*8;
                const bf16x8 w0 = ldw<WSB>(qkv_w, hqkv, (256 + h*32 + lo)      * 128 + coff);
                const bf16x8 w1 = ldw<WSB>(qkv_w, hqkv, (256 + h*32 + 16 + lo) * 128 + coff);
                #pragma unroll
                for (int m = 0; m < 4; ++m) {
                    av[m][0] = MFMA(xv[m], w0, av[m][0]);
                    av[m][1] = MFMA(xv[m], w1, av[m][1]);
                }
            }
            const float bv0 = qkv_b[256 + h*32 + lo];
            const float bv1 = qkv_b[256 + h*32 + 16 + lo];
            #pragma unroll
            for (int kb = 0; kb < 2; ++kb) {
                vf[0][kb] = cat8(pk4c(av[kb*2][0], bv0), pk4c(av[kb*2 + 1][0], bv0));
                vf[1][kb] = cat8(pk4c(av[kb*2][1], bv1), pk4c(av[kb*2 + 1][1], bv1));
            }
        }
        {
            f32x4 o0[2][4];
            #pragma unroll
            for (int o = 0; o < 2; ++o)
                #pragma unroll
                for (int n = 0; n < 4; ++n) o0[o][n] = FZ;
            #pragma unroll
            for (int kb = 0; kb < 2; ++kb)
                #pragma unroll
                for (int o = 0; o < 2; ++o)
                    #pragma unroll
                    for (int n = 0; n < 4; ++n)
                        o0[o][n] = MFMA(vf[o][kb], pf[kb][n], o0[o][n]);
            #pragma unroll
            for (int o = 0; o < 2; ++o)
                #pragma unroll
                for (int n = 0; n < 4; ++n)
                    ob[h][o][n] = pk4s(o0[o][n], rinv[n]);
        }
    }

    #pragma unroll
    for (int h = 0; h < 4; ++h)
        #pragma unroll
        for (int o = 0; o < 2; ++o) {
            const int cb = h*64 + o*32 + hi*8;
            #pragma unroll
            for (int n = 0; n < 4; ++n) {
                const int t = n*16 + lo;
                *(bf16x4*)(sX + t*256 + (cb ^ SW(t))) = ob[h][o][n];
            }
        }

    #pragma unroll
    for (int c4 = 0; c4 < 4; ++c4) {
        f32x4 pr[2][4];
        #pragma unroll
        for (int a = 0; a < 2; ++a)
            #pragma unroll
            for (int n = 0; n < 4; ++n) pr[a][n] = FZ;
        #pragma unroll
        for (int kb = 0; kb < 4; ++kb) {
            bf16x8 af[4];
            #pragma unroll
            for (int n = 0; n < 4; ++n) {
                const int row = n*16 + lo;
                af[n] = *(const bf16x8*)(sX + row*256 + ((kb*64 + hi*16) ^ SW(row)));
            }
            const int coff = kb*32 + hi*8;
            const bf16x8 w0 = ldw<WSB>(proj_w, hproj, (c4*32 + lo)      * 128 + coff);
            const bf16x8 w1 = ldw<WSB>(proj_w, hproj, (c4*32 + 16 + lo) * 128 + coff);
            #pragma unroll
            for (int n = 0; n < 4; ++n) {
                pr[0][n] = MFMA(w0, af[n], pr[0][n]);
                pr[1][n] = MFMA(w1, af[n], pr[1][n]);
            }
        }
        #pragma unroll
        for (int a = 0; a < 2; ++a) {
            const int ocb = c4*32 + a*16 + hi*4;
            const float4 pb = *(const float4*)(proj_b + ocb);
            #pragma unroll
            for (int n = 0; n < 4; ++n) {
                const int t = n*16 + lo;
                int hh = wy*8 + (t >> 3) + 4; if (hh >= HIMG) hh -= HIMG;
                int ww = wx*8 + (t & 7)  + 4; if (ww >= HIMG) ww -= HIMG;
                float* op = out + (long)(batch*128 + ocb) * HWSZ + hh*HIMG + ww;
                op[0]      = pr[a][n][0] + pb.x;
                op[HWSZ]   = pr[a][n][1] + pb.y;
                op[2*HWSZ] = pr[a][n][2] + pb.z;
                op[3*HWSZ] = pr[a][n][3] + pb.w;
            }
        }
    }
}

extern "C" void kernel_launch(void* const* d_in, const int* in_sizes, int n_in,
                              void* d_out, int out_size, void* d_ws, size_t ws_size,
                              hipStream_t stream) {
    const float* x      = (const float*)d_in[0];
    const float* qkv_w  = (const float*)d_in[1];
    const float* qkv_b  = (const float*)d_in[2];
    const float* proj_w = (const float*)d_in[3];
    const float* proj_b = (const float*)d_in[4];
    const float* rpb    = (const float*)d_in[5];
    float* out = (float*)d_out;

    // ws bytes: [0,64K) wbias f32 | [64K,160K) hqkv | [160K,192K) hproj
    //           [192K,256K) wbf f32 | [256K,352K) hqkvf | [352K,384K) hprojf
    //           [384K, +75.5M) obuf
    const size_t SETUP = 393216;
    const size_t OSZ   = (size_t)4608 * 16384;

    float* wbias = (float*)d_ws;
    bf16*  hqkv  = (bf16*)((char*)d_ws + 65536);
    bf16*  hproj = (bf16*)((char*)d_ws + 163840);
    float* wbf   = (float*)((char*)d_ws + 196608);
    bf16*  hqkvf = (bf16*)((char*)d_ws + 262144);
    bf16*  hprojf= (bf16*)((char*)d_ws + 360448);
    bf16*  obuf  = (bf16*)((char*)d_ws + SETUP);

    if (ws_size >= SETUP + OSZ) {
        setup_ws<<<640, 256, 0, stream>>>(rpb, qkv_w, proj_w, wbias, hqkv, hproj,
                                          wbf, hqkvf, hprojf);
        qkv_attn<<<4608, 256, 0, stream>>>(x, qkv_b, hqkvf, wbf, obuf);
        proj_rows<<<1536, 512, 0, stream>>>(obuf, hprojf, proj_b, out);
    } else if (ws_size >= SETUP) {
        setup_ws<<<640, 256, 0, stream>>>(rpb, qkv_w, proj_w, wbias, hqkv, hproj,
                                          wbf, hqkvf, hprojf);
        swin_fused<1><<<4608, 64, 0, stream>>>(x, qkv_w, qkv_b, proj_w, proj_b, rpb,
                                               wbias, hqkv, hproj, out);
    } else {
        swin_fused<0><<<4608, 64, 0, stream>>>(x, qkv_w, qkv_b, proj_w, proj_b, rpb,
                                               nullptr, nullptr, nullptr, out);
    }
}

// Round 17
// 147.544 us; speedup vs baseline: 2.2200x; 1.0186x over previous
//
#include <hip/hip_runtime.h>

#define HIMG 192
#define HWSZ (192*192)
#define NWX  24

typedef __bf16 bf16;
typedef __bf16 bf16x2 __attribute__((ext_vector_type(2)));
typedef __bf16 bf16x4 __attribute__((ext_vector_type(4)));
typedef __bf16 bf16x8 __attribute__((ext_vector_type(8)));
typedef float  f32x4  __attribute__((ext_vector_type(4)));

#define MFMA(a,b,c) __builtin_amdgcn_mfma_f32_16x16x32_bf16((a),(b),(c),0,0,0)
#define SW(r) (((((r)&7) ^ ((((r)>>3)&1)<<2))) << 4)

static __device__ __forceinline__ bf16x8 ldg8(const float* p) {
    const float4 u = ((const float4*)p)[0];
    const float4 v = ((const float4*)p)[1];
    bf16x8 r;
    r[0]=(bf16)u.x; r[1]=(bf16)u.y; r[2]=(bf16)u.z; r[3]=(bf16)u.w;
    r[4]=(bf16)v.x; r[5]=(bf16)v.y; r[6]=(bf16)v.z; r[7]=(bf16)v.w;
    return r;
}
template<int WSB>
static __device__ __forceinline__ bf16x8 ldw(const float* wf, const bf16* wh, int off) {
    if (WSB) return *(const bf16x8*)(wh + off);
    return ldg8(wf + off);
}
static __device__ __forceinline__ bf16x4 pk4b(f32x4 v, float4 b) {
    bf16x4 r; r[0]=(bf16)(v[0]+b.x); r[1]=(bf16)(v[1]+b.y);
    r[2]=(bf16)(v[2]+b.z); r[3]=(bf16)(v[3]+b.w); return r;
}
static __device__ __forceinline__ bf16x4 pk4bs(f32x4 v, float4 b, float s) {
    bf16x4 r; r[0]=(bf16)((v[0]+b.x)*s); r[1]=(bf16)((v[1]+b.y)*s);
    r[2]=(bf16)((v[2]+b.z)*s); r[3]=(bf16)((v[3]+b.w)*s); return r;
}
static __device__ __forceinline__ bf16x4 pk4c(f32x4 v, float b) {
    bf16x4 r; r[0]=(bf16)(v[0]+b); r[1]=(bf16)(v[1]+b);
    r[2]=(bf16)(v[2]+b); r[3]=(bf16)(v[3]+b); return r;
}
static __device__ __forceinline__ bf16x4 pk4s(f32x4 v, float s) {
    bf16x4 r; r[0]=(bf16)(v[0]*s); r[1]=(bf16)(v[1]*s);
    r[2]=(bf16)(v[2]*s); r[3]=(bf16)(v[3]*s); return r;
}
static __device__ __forceinline__ bf16x4 pk4(f32x4 v) {
    bf16x4 r; r[0]=(bf16)v[0]; r[1]=(bf16)v[1]; r[2]=(bf16)v[2]; r[3]=(bf16)v[3]; return r;
}
static __device__ __forceinline__ bf16x8 cat8(bf16x4 a, bf16x4 b) {
    bf16x8 r; r[0]=a[0]; r[1]=a[1]; r[2]=a[2]; r[3]=a[3];
    r[4]=b[0]; r[5]=b[1]; r[6]=b[2]; r[7]=b[3]; return r;
}
static __device__ __forceinline__ f32x4 splat4(float b) {
    f32x4 r; r[0]=b; r[1]=b; r[2]=b; r[3]=b; return r;
}
static __device__ __forceinline__ f32x4 f4of(float4 b) {
    f32x4 r; r[0]=b.x; r[1]=b.y; r[2]=b.z; r[3]=b.w; return r;
}
static __device__ __forceinline__ f32x4 f4ofs(float4 b, float s) {
    f32x4 r; r[0]=b.x*s; r[1]=b.y*s; r[2]=b.z*s; r[3]=b.w*s; return r;
}

// ---------------------------------------------------------------------------
// Setup: parameter tables incl. frag-layout (lane-coalesced) copies.
// hqkvf Q-section is pre-scaled by 32^-0.5.
// ---------------------------------------------------------------------------
__global__ __launch_bounds__(256) void setup_ws(const float* __restrict__ rpb,
                                                const float* __restrict__ qkv_w,
                                                const float* __restrict__ proj_w,
                                                float* __restrict__ wbias,
                                                bf16* __restrict__ hqkv,
                                                bf16* __restrict__ hproj,
                                                float* __restrict__ wbf,
                                                bf16* __restrict__ hqkvf,
                                                bf16* __restrict__ hprojf) {
    const int e = blockIdx.x * 256 + threadIdx.x;   // 0..163839
    if (e < 16384) {
        const int h = e >> 12, i = (e >> 6) & 63, j = e & 63;
        const int dy = (i >> 3) - (j >> 3) + 7;
        const int dx = (i & 7)  - (j & 7)  + 7;
        wbias[e] = rpb[(dy * 15 + dx) * 4 + h];
    } else if (e < 65536) {
        const int i = e - 16384;
        hqkv[i] = (bf16)qkv_w[i];
    } else if (e < 81920) {
        const int i = e - 65536;
        hproj[i] = (bf16)proj_w[i];
    } else if (e < 98304) {
        const int t = e - 81920;
        const int r = t & 3, lane = (t >> 2) & 63;
        const int m = (t >> 8) & 3, n = (t >> 10) & 3, h = t >> 12;
        const int lo = lane & 15, hi = lane >> 4;
        const int i_ = n*16 + lo;
        const int j_ = (m >> 1)*32 + hi*8 + (m & 1)*4 + r;
        const int dy = (i_ >> 3) - (j_ >> 3) + 7;
        const int dx = (i_ & 7)  - (j_ & 7)  + 7;
        wbf[t] = rpb[(dy * 15 + dx) * 4 + h];
    } else if (e < 147456) {
        const int t = e - 98304;
        const int el = t & 7, lane = (t >> 3) & 63;
        const int a = (t >> 9) & 1, kb = (t >> 10) & 3;
        const int h = (t >> 12) & 3, ph = t >> 14;
        const int lo = lane & 15, hi = lane >> 4;
        const int prow = ((lo >> 2) << 3) + (lo & 3);
        const int row = (ph == 2) ? (256 + h*32 + a*16 + lo)
                                  : (ph*128 + h*32 + prow + a*4);
        const int col = kb*32 + hi*8 + el;
        float wv_ = qkv_w[row*128 + col];
        if (ph == 0) wv_ *= 0.17677669529663687f;   // fold attention scale into Wq
        hqkvf[t] = (bf16)wv_;
    } else {
        const int t = e - 147456;
        const int el = t & 7, lane = (t >> 3) & 63;
        const int tA = (t >> 9) & 3, kb = (t >> 11) & 3, oh = t >> 13;
        const int lo = lane & 15, hi = lane >> 4;
        const int row = oh*64 + tA*16 + lo;
        const int col = kb*32 + hi*8 + el;
        hprojf[t] = (bf16)proj_w[row*128 + col];
    }
}

// ---------------------------------------------------------------------------
// Fused gather + QKV + attention, register-slimmed phases:
//   gather -> Q -> K -> S+softmax(pf) -> {V fused with PV per o-half}.
// Peak accumulator live-set cut from 64 to ~32 regs -> total demand ~112,
// allowing __launch_bounds__(256,4) (cap 128) WITHOUT spilling: 4 blocks/CU.
// Trims: biases as MFMA C-init, SCALE folded into Wq, no-max-sub softmax.
// ---------------------------------------------------------------------------
__global__ __launch_bounds__(256, 4)
void qkv_attn(const float* __restrict__ x, const float* __restrict__ qkv_b,
              const bf16* __restrict__ hqkvf, const float* __restrict__ wbf,
              bf16* __restrict__ obuf)
{
    __shared__ char sX[16384];   // [64 tok][256B ch] bf16, col ^ SW(tok)
    const int tid  = threadIdx.x;
    const int lane = tid & 63;
    const int h    = tid >> 6;
    const int lo   = lane & 15;
    const int hi   = lane >> 4;

    const int bid   = blockIdx.x;        // == win index
    const int batch = bid & 7;
    const int wrem  = bid >> 3;
    const int wy    = wrem / NWX;
    const int wx    = wrem - wy * NWX;

    const float SCALE = 0.17677669529663687f;
    const int prow = ((lo >> 2) << 3) + (lo & 3);

    // ---- gather+roll -> LDS: 512 (chq,row,w4) tiles, 4 planes per tile ----
    {
        const int hbase = wy*8 + 4;
        const int wbase = wx*8 + 4;
        #pragma unroll
        for (int k = 0; k < 2; ++k) {
            const int id  = k*256 + tid;     // 0..511
            const int w4  = id & 1;
            const int row = (id >> 1) & 7;
            const int chq = id >> 4;         // channel quad 0..31
            int hh = hbase + row;  if (hh >= HIMG) hh -= HIMG;
            int ww = wbase + w4*4; if (ww >= HIMG) ww -= HIMG;
            const float* p0 = x + (size_t)(batch*128 + chq*4) * HWSZ + hh*HIMG + ww;
            const float4 a = *(const float4*)p0;
            const float4 b = *(const float4*)(p0 + HWSZ);
            const float4 c = *(const float4*)(p0 + 2*HWSZ);
            const float4 d = *(const float4*)(p0 + 3*HWSZ);
            const int t0 = row*8 + w4*4;
            #pragma unroll
            for (int e = 0; e < 4; ++e) {
                const int t = t0 + e;
                bf16x4 pr;
                pr[0] = (bf16)(&a.x)[e]; pr[1] = (bf16)(&b.x)[e];
                pr[2] = (bf16)(&c.x)[e]; pr[3] = (bf16)(&d.x)[e];
                *(bf16x4*)(sX + t*256 + ((8*chq) ^ SW(t))) = pr;
            }
        }
    }
    __syncthreads();   // only barrier

    const bf16* const wQ = hqkvf + h * 4096;            // pre-scaled
    const bf16* const wK = hqkvf + 16384 + h * 4096;
    const bf16* const wV = hqkvf + 32768 + h * 4096;

    bf16x8 qf[4], kf[4];

    // ---- Q^T = (S*Wq) @ X^T, bias via C-init ----
    {
        const float4 b0 = *(const float4*)(qkv_b + h*32 + hi*8);
        const float4 b1 = *(const float4*)(qkv_b + h*32 + hi*8 + 4);
        const f32x4 c0 = f4ofs(b0, SCALE);
        const f32x4 c1 = f4ofs(b1, SCALE);
        f32x4 acc[2][4];
        #pragma unroll
        for (int n = 0; n < 4; ++n) { acc[0][n] = c0; acc[1][n] = c1; }
        #pragma unroll
        for (int kb = 0; kb < 4; ++kb) {
            bf16x8 xf[4];
            #pragma unroll
            for (int n = 0; n < 4; ++n) {
                const int row = n*16 + lo;
                xf[n] = *(const bf16x8*)(sX + row*256 + ((kb*64 + hi*16) ^ SW(row)));
            }
            const bf16x8 w0 = *(const bf16x8*)(wQ + (kb*2    )*512 + lane*8);
            const bf16x8 w1 = *(const bf16x8*)(wQ + (kb*2 + 1)*512 + lane*8);
            #pragma unroll
            for (int n = 0; n < 4; ++n) {
                acc[0][n] = MFMA(w0, xf[n], acc[0][n]);
                acc[1][n] = MFMA(w1, xf[n], acc[1][n]);
            }
        }
        #pragma unroll
        for (int n = 0; n < 4; ++n)
            qf[n] = cat8(pk4(acc[0][n]), pk4(acc[1][n]));
    }

    // ---- K^T only (A-frags, token-permuted rows), bias via C-init ----
    {
        const float4 k0 = *(const float4*)(qkv_b + 128 + h*32 + hi*8);
        const float4 k1 = *(const float4*)(qkv_b + 128 + h*32 + hi*8 + 4);
        const f32x4 ck0 = f4of(k0), ck1 = f4of(k1);
        f32x4 ak[2][4];
        #pragma unroll
        for (int m = 0; m < 4; ++m) { ak[0][m] = ck0; ak[1][m] = ck1; }
        #pragma unroll
        for (int kb = 0; kb < 4; ++kb) {
            bf16x8 xf[4];
            #pragma unroll
            for (int m = 0; m < 4; ++m) {
                const int row = (m >> 1)*32 + (m & 1)*4 + prow;
                xf[m] = *(const bf16x8*)(sX + row*256 + ((kb*64 + hi*16) ^ SW(row)));
            }
            const bf16x8 wk0 = *(const bf16x8*)(wK + (kb*2    )*512 + lane*8);
            const bf16x8 wk1 = *(const bf16x8*)(wK + (kb*2 + 1)*512 + lane*8);
            #pragma unroll
            for (int m = 0; m < 4; ++m) {
                ak[0][m] = MFMA(wk0, xf[m], ak[0][m]);
                ak[1][m] = MFMA(wk1, xf[m], ak[1][m]);
            }
        }
        #pragma unroll
        for (int m = 0; m < 4; ++m)
            kf[m] = cat8(pk4(ak[0][m]), pk4(ak[1][m]));
    }

    // ---- S^T = K @ Q^T + (bias+mask as C-init); softmax (no max-sub) ----
    const bool ey = (wy == 23), ex = (wx == 23);
    const bool edge = ey || ex;
    const float* const wbh = wbf + h * 4096;
    bf16x8 pf[2][4];
    float rinv[4];
    #pragma unroll
    for (int n = 0; n < 4; ++n) {
        const int i_ = n*16 + lo;
        const int yi = i_ >> 3, xi = i_ & 7;
        const int ri = (ey ? (yi < 4 ? 1 : 2) : 0) * 3 + (ex ? (xi < 4 ? 1 : 2) : 0);
        f32x4 sc[4];
        #pragma unroll
        for (int m = 0; m < 4; ++m) {
            f32x4 ci = *(const f32x4*)(wbh + (n*4 + m)*256 + lane*4);
            if (edge) {
                #pragma unroll
                for (int r = 0; r < 4; ++r) {
                    const int j_ = (m >> 1)*32 + hi*8 + (m & 1)*4 + r;
                    const int yj = j_ >> 3, xj = j_ & 7;
                    const int rj = (ey ? (yj < 4 ? 1 : 2) : 0) * 3 + (ex ? (xj < 4 ? 1 : 2) : 0);
                    ci[r] += (ri != rj) ? -100.0f : 0.0f;
                }
            }
            sc[m] = MFMA(kf[m], qf[n], ci);
        }
        float sum = 0.f;
        #pragma unroll
        for (int m = 0; m < 4; ++m)
            #pragma unroll
            for (int r = 0; r < 4; ++r) {
                const float p = __expf(sc[m][r]);
                sc[m][r] = p; sum += p;
            }
        sum += __shfl_xor(sum, 16);
        sum += __shfl_xor(sum, 32);
        rinv[n] = 1.0f / sum;
        pf[0][n] = cat8(pk4(sc[0]), pk4(sc[1]));
        pf[1][n] = cat8(pk4(sc[2]), pk4(sc[3]));
    }

    // ---- V fused with PV, one output-half at a time (low accum pressure) ----
    bf16* const ob = obuf + (size_t)bid * 8192 + h * 2048;
    #pragma unroll
    for (int o = 0; o < 2; ++o) {
        const float bv = qkv_b[256 + h*32 + o*16 + lo];
        const f32x4 cv = splat4(bv);
        f32x4 av[4];
        #pragma unroll
        for (int m = 0; m < 4; ++m) av[m] = cv;
        #pragma unroll
        for (int kb = 0; kb < 4; ++kb) {
            bf16x8 xf[4];
            #pragma unroll
            for (int m = 0; m < 4; ++m) {
                const int row = (m >> 1)*32 + (m & 1)*4 + prow;
                xf[m] = *(const bf16x8*)(sX + row*256 + ((kb*64 + hi*16) ^ SW(row)));
            }
            const bf16x8 wv = *(const bf16x8*)(wV + (kb*2 + o)*512 + lane*8);
            #pragma unroll
            for (int m = 0; m < 4; ++m)
                av[m] = MFMA(xf[m], wv, av[m]);
        }
        bf16x8 vf[2];
        #pragma unroll
        for (int kb = 0; kb < 2; ++kb)
            vf[kb] = cat8(pk4(av[kb*2]), pk4(av[kb*2 + 1]));

        f32x4 o0[4];
        #pragma unroll
        for (int n = 0; n < 4; ++n) { o0[n][0]=0.f; o0[n][1]=0.f; o0[n][2]=0.f; o0[n][3]=0.f; }
        #pragma unroll
        for (int kb = 0; kb < 2; ++kb)
            #pragma unroll
            for (int n = 0; n < 4; ++n)
                o0[n] = MFMA(vf[kb], pf[kb][n], o0[n]);

        #pragma unroll
        for (int n = 0; n < 4; ++n)
            *(bf16x4*)(ob + (n*2 + o)*256 + lane*4) = pk4s(o0[n], rinv[n]);
    }
}

// ---------------------------------------------------------------------------
// Projection by image rows (unchanged).
// ---------------------------------------------------------------------------
__global__ __launch_bounds__(512, 3)
void proj_rows(const bf16* __restrict__ obuf, const bf16* __restrict__ hprojf,
               const float* __restrict__ proj_b, float* __restrict__ out)
{
    __shared__ char sR[49152];   // [192 tok][256B bf16], col ^ SW(tok)
    const int tid  = threadIdx.x;
    const int lane = tid & 63;
    const int wv   = tid >> 6;
    const int lo   = lane & 15;
    const int hi   = lane >> 4;

    const int bid   = blockIdx.x;        // 1536 = 8 batch x 192 rows
    const int batch = bid & 7;
    const int hh    = bid >> 3;          // output row 0..191
    int hr = hh + 188; if (hr >= 192) hr -= 192;   // rolled-frame row
    const int wy = hr >> 3, iy = hr & 7;
    const int n_ = iy >> 1;

    #pragma unroll
    for (int k = 0; k < 6; ++k) {
        const int i  = tid + k*512;      // 0..3071
        const int wr = i >> 4;           // rolled-frame col
        const int cc = i & 15;           // 8-channel chunk
        const int wxx = wr >> 3, ix = wr & 7;
        const int win = (wy*NWX + wxx)*8 + batch;
        const int lo2 = (iy & 1)*8 + ix;
        const int hg = cc >> 2, oo = (cc >> 1) & 1, hp = cc & 1;
        const bf16* bp = obuf + (size_t)win*8192 + hg*2048 + (n_*2 + oo)*256;
        const bf16x4 p0 = *(const bf16x4*)(bp + ((hp*2    )*16 + lo2)*4);
        const bf16x4 p1 = *(const bf16x4*)(bp + ((hp*2 + 1)*16 + lo2)*4);
        int wo = wr + 4; if (wo >= 192) wo -= 192;
        *(bf16x8*)(sR + wo*256 + ((cc*16) ^ SW(wo))) = cat8(p0, p1);
    }
    __syncthreads();

    const int q  = wv >> 1;
    const int oh = wv & 1;
    const f32x4 FZ = {0.f, 0.f, 0.f, 0.f};
    f32x4 acc[4][3];
    #pragma unroll
    for (int tA = 0; tA < 4; ++tA)
        #pragma unroll
        for (int tN = 0; tN < 3; ++tN) acc[tA][tN] = FZ;

    #pragma unroll
    for (int kb = 0; kb < 4; ++kb) {
        bf16x8 of[3];
        #pragma unroll
        for (int tN = 0; tN < 3; ++tN) {
            const int tok = q*48 + tN*16 + lo;
            of[tN] = *(const bf16x8*)(sR + tok*256 + ((kb*64 + hi*16) ^ SW(tok)));
        }
        bf16x8 wf[4];
        #pragma unroll
        for (int tA = 0; tA < 4; ++tA)
            wf[tA] = *(const bf16x8*)(hprojf + (size_t)(((oh*4 + kb)*4 + tA)*64 + lane)*8);
        #pragma unroll
        for (int tA = 0; tA < 4; ++tA)
            #pragma unroll
            for (int tN = 0; tN < 3; ++tN)
                acc[tA][tN] = MFMA(of[tN], wf[tA], acc[tA][tN]);
    }

    #pragma unroll
    for (int tA = 0; tA < 4; ++tA) {
        const int oc = oh*64 + tA*16 + lo;
        const float pb = proj_b[oc];
        float* const orow = out + (size_t)(batch*128 + oc) * HWSZ + hh*HIMG;
        #pragma unroll
        for (int tN = 0; tN < 3; ++tN) {
            const int tb = q*48 + tN*16 + hi*4;
            float4 v;
            v.x = acc[tA][tN][0] + pb;
            v.y = acc[tA][tN][1] + pb;
            v.z = acc[tA][tN][2] + pb;
            v.w = acc[tA][tN][3] + pb;
            *(float4*)(orow + tb) = v;
        }
    }
}

// ---------------------------------------------------------------------------
// Fallback: fused one-wave-per-window kernel (round-6), for small workspaces.
// ---------------------------------------------------------------------------
template<int WSB>
__global__ __launch_bounds__(64, 2)
void swin_fused(const float* __restrict__ x, const float* __restrict__ qkv_w,
                const float* __restrict__ qkv_b, const float* __restrict__ proj_w,
                const float* __restrict__ proj_b, const float* __restrict__ rpb,
                const float* __restrict__ wb, const bf16* __restrict__ hqkv,
                const bf16* __restrict__ hproj, float* __restrict__ out)
{
    __shared__ char sX[16384];

    const int lane = threadIdx.x & 63;
    const int lo   = lane & 15;
    const int hi   = lane >> 4;

    const int bid   = blockIdx.x;
    const int batch = bid & 7;
    const int wrem  = bid >> 3;
    const int wy    = wrem / NWX;
    const int wx    = wrem - wy * NWX;
    const long xbase = (long)batch * 128 * HWSZ;

    const f32x4 FZ = {0.f, 0.f, 0.f, 0.f};
    const float SCALE = 0.17677669529663687f;
    const int prow = ((lo >> 2) << 3) + (lo & 3);

    {
        int hh = wy*8 + (lane >> 3) + 4; if (hh >= HIMG) hh -= HIMG;
        int ww = wx*8 + (lane & 7)  + 4; if (ww >= HIMG) ww -= HIMG;
        const float* xp = x + xbase + hh * HIMG + ww;
        char* const wp = sX + lane * 256;
        const int swz = SW(lane);
        #pragma unroll
        for (int g = 0; g < 16; ++g) {
            bf16x8 v;
            #pragma unroll
            for (int e = 0; e < 8; ++e) v[e] = (bf16)xp[(g*8 + e) * HWSZ];
            *(bf16x8*)(wp + ((16*g) ^ swz)) = v;
        }
    }

    const bool ey = (wy == 23), ex = (wx == 23);
    const bool edge = ey || ex;

    bf16x4 ob[4][2][4];

    #pragma unroll
    for (int h = 0; h < 4; ++h) {
        bf16x8 qf[4], kf[4];
        {
            f32x4 acc[2][4];
            #pragma unroll
            for (int a = 0; a < 2; ++a)
                #pragma unroll
                for (int n = 0; n < 4; ++n) acc[a][n] = FZ;
            #pragma unroll
            for (int kb = 0; kb < 4; ++kb) {
                bf16x8 xf[4];
                #pragma unroll
                for (int n = 0; n < 4; ++n) {
                    const int row = n*16 + lo;
                    xf[n] = *(const bf16x8*)(sX + row*256 + ((kb*64 + hi*16) ^ SW(row)));
                }
                const int coff = kb*32 + hi*8;
                const bf16x8 w0 = ldw<WSB>(qkv_w, hqkv, (h*32 + prow    ) * 128 + coff);
                const bf16x8 w1 = ldw<WSB>(qkv_w, hqkv, (h*32 + prow + 4) * 128 + coff);
                #pragma unroll
                for (int n = 0; n < 4; ++n) {
                    acc[0][n] = MFMA(w0, xf[n], acc[0][n]);
                    acc[1][n] = MFMA(w1, xf[n], acc[1][n]);
                }
            }
            const float4 b0 = *(const float4*)(qkv_b + h*32 + hi*8);
            const float4 b1 = *(const float4*)(qkv_b + h*32 + hi*8 + 4);
            #pragma unroll
            for (int n = 0; n < 4; ++n)
                qf[n] = cat8(pk4bs(acc[0][n], b0, SCALE), pk4bs(acc[1][n], b1, SCALE));
        }
        {
            f32x4 ak[2][4];
            #pragma unroll
            for (int a = 0; a < 2; ++a)
                #pragma unroll
                for (int m = 0; m < 4; ++m) ak[a][m] = FZ;
            #pragma unroll
            for (int kb = 0; kb < 4; ++kb) {
                bf16x8 xf[4];
                #pragma unroll
                for (int m = 0; m < 4; ++m) {
                    const int row = (m >> 1)*32 + (m & 1)*4 + prow;
                    xf[m] = *(const bf16x8*)(sX + row*256 + ((kb*64 + hi*16) ^ SW(row)));
                }
                const int coff = kb*32 + hi*8;
                const bf16x8 w0 = ldw<WSB>(qkv_w, hqkv, (128 + h*32 + prow    ) * 128 + coff);
                const bf16x8 w1 = ldw<WSB>(qkv_w, hqkv, (128 + h*32 + prow + 4) * 128 + coff);
                #pragma unroll
                for (int m = 0; m < 4; ++m) {
                    ak[0][m] = MFMA(w0, xf[m], ak[0][m]);
                    ak[1][m] = MFMA(w1, xf[m], ak[1][m]);
                }
            }
            const float4 b0 = *(const float4*)(qkv_b + 128 + h*32 + hi*8);
            const float4 b1 = *(const float4*)(qkv_b + 128 + h*32 + hi*8 + 4);
            #pragma unroll
            for (int m = 0; m < 4; ++m)
                kf[m] = cat8(pk4b(ak[0][m], b0), pk4b(ak[1][m], b1));
        }

        f32x4 s2[4][4];
        const float* wbh = wb + h * 4096;
        #pragma unroll
        for (int n = 0; n < 4; ++n) {
            const int i_ = n*16 + lo;
            const int yi = i_ >> 3, xi = i_ & 7;
            const int ri = (ey ? (yi < 4 ? 1 : 2) : 0) * 3 + (ex ? (xi < 4 ? 1 : 2) : 0);
            #pragma unroll
            for (int m = 0; m < 4; ++m) {
                const int j0 = (m >> 1)*32 + hi*8 + (m & 1)*4;
                f32x4 ci;
                if (WSB) ci = *(const f32x4*)(wbh + i_*64 + j0);
                else {
                    #pragma unroll
                    for (int r = 0; r < 4; ++r) {
                        const int j_ = j0 + r;
                        ci[r] = rpb[((yi - (j_ >> 3) + 7) * 15 + (xi - (j_ & 7) + 7)) * 4 + h];
                    }
                }
                if (edge) {
                    #pragma unroll
                    for (int r = 0; r < 4; ++r) {
                        const int j_ = j0 + r;
                        const int yj = j_ >> 3, xj = j_ & 7;
                        const int rj = (ey ? (yj < 4 ? 1 : 2) : 0) * 3 + (ex ? (xj < 4 ? 1 : 2) : 0);
                        ci[r] += (ri != rj) ? -100.0f : 0.0f;
                    }
                }
                s2[m][n] = MFMA(kf[m], qf[n], ci);
            }
        }
        float rinv[4];
        #pragma unroll
        for (int n = 0; n < 4; ++n) {
            float mx = -1e30f;
            #pragma unroll
            for (int m = 0; m < 4; ++m)
                #pragma unroll
                for (int r = 0; r < 4; ++r) mx = fmaxf(mx, s2[m][n][r]);
            mx = fmaxf(mx, __shfl_xor(mx, 16));
            mx = fmaxf(mx, __shfl_xor(mx, 32));
            float sum = 0.f;
            #pragma unroll
            for (int m = 0; m < 4; ++m)
                #pragma unroll
                for (int r = 0; r < 4; ++r) {
                    const float p = __expf(s2[m][n][r] - mx);
                    s2[m][n][r] = p; sum += p;
                }
            sum += __shfl_xor(sum, 16);
            sum += __shfl_xor(sum, 32);
            rinv[n] = 1.0f / sum;
        }
        bf16x8 pf[2][4];
        #pragma unroll
        for (int kb = 0; kb < 2; ++kb)
            #pragma unroll
            for (int n = 0; n < 4; ++n)
                pf[kb][n] = cat8(pk4(s2[kb*2][n]), pk4(s2[kb*2 + 1][n]));

        bf16x8 vf[2][2];
        {
            f32x4 av[4][2];
            #pragma unroll
            for (int m = 0; m < 4; ++m) { av[m][0] = FZ; av[m][1] = FZ; }
            #pragma unroll
            for (int kb = 0; kb < 4; ++kb) {
                bf16x8 xv[4];
                #pragma unroll
                for (int m = 0; m < 4; ++m) {
                    const int row = (m >> 1)*32 + (m & 1)*4 + prow;
                    xv[m] = *(const bf16x8*)(sX + row*256 + ((kb*64 + hi*16) ^ SW(row)));
                }
                const int coff = kb*32 + hi*8;
                const bf16x8 w0 = ldw<WSB>(qkv_w, hqkv, (256 + h*32 + lo)      * 128 + coff);
                const bf16x8 w1 = ldw<WSB>(qkv_w, hqkv, (256 + h*32 + 16 + lo) * 128 + coff);
                #pragma unroll
                for (int m = 0; m < 4; ++m) {
                    av[m][0] = MFMA(xv[m], w0, av[m][0]);
                    av[m][1] = MFMA(xv[m], w1, av[m][1]);
                }
            }
            const float bv0 = qkv_b[256 + h*32 + lo];
            const float bv1 = qkv_b[256 + h*32 + 16 + lo];
            #pragma unroll
            for (int kb = 0; kb < 2; ++kb) {
                vf[0][kb] = cat8(pk4c(av[kb*2][0], bv0), pk4c(av[kb*2 + 1][0], bv0));
                vf[1][kb] = cat8(pk4c(av[kb*2][1], bv1), pk4c(av[kb*2 + 1][1], bv1));
            }
        }
        {
            f32x4 o0[2][4];
            #pragma unroll
            for (int o = 0; o < 2; ++o)
                #pragma unroll
                for (int n = 0; n < 4; ++n) o0[o][n] = FZ;
            #pragma unroll
            for (int kb = 0; kb < 2; ++kb)
                #pragma unroll
                for (int o = 0; o < 2; ++o)
                    #pragma unroll
                    for (int n = 0; n < 4; ++n)
                        o0[o][n] = MFMA(vf[o][kb], pf[kb][n], o0[o][n]);
            #pragma unroll
            for (int o = 0; o < 2; ++o)
                #pragma unroll
                for (int n = 0; n < 4; ++n)
                    ob[h][o][n] = pk4s(o0[o][n], rinv[n]);
        }
    }

    #pragma unroll
    for (int h = 0; h < 4; ++h)
        #pragma unroll
        for (int o = 0; o < 2; ++o) {
            const int cb = h*64 + o*32 + hi*8;
            #pragma unroll
            for (int n = 0; n < 4; ++n) {
                const int t = n*16 + lo;
                *(bf16x4*)(sX + t*256 + (cb ^ SW(t))) = ob[h][o][n];
            }
        }

    #pragma unroll
    for (int c4 = 0; c4 < 4; ++c4) {
        f32x4 pr[2][4];
        #pragma unroll
        for (int a = 0; a < 2; ++a)
            #pragma unroll
            for (int n = 0; n < 4; ++n) pr[a][n] = FZ;
        #pragma unroll
        for (int kb = 0; kb < 4; ++kb) {
            bf16x8 af[4];
            #pragma unroll
            for (int n = 0; n < 4; ++n) {
                const int row = n*16 + lo;
                af[n] = *(const bf16x8*)(sX + row*256 + ((kb*64 + hi*16) ^ SW(row)));
            }
            const int coff = kb*32 + hi*8;
            const bf16x8 w0 = ldw<WSB>(proj_w, hproj, (c4*32 + lo)      * 128 + coff);
            const bf16x8 w1 = ldw<WSB>(proj_w, hproj, (c4*32 + 16 + lo) * 128 + coff);
            #pragma unroll
            for (int n = 0; n < 4; ++n) {
                pr[0][n] = MFMA(w0, af[n], pr[0][n]);
                pr[1][n] = MFMA(w1, af[n], pr[1][n]);
            }
        }
        #pragma unroll
        for (int a = 0; a < 2; ++a) {
            const int ocb = c4*32 + a*16 + hi*4;
            const float4 pb = *(const float4*)(proj_b + ocb);
            #pragma unroll
            for (int n = 0; n < 4; ++n) {
                const int t = n*16 + lo;
                int hh = wy*8 + (t >> 3) + 4; if (hh >= HIMG) hh -= HIMG;
                int ww = wx*8 + (t & 7)  + 4; if (ww >= HIMG) ww -= HIMG;
                float* op = out + (long)(batch*128 + ocb) * HWSZ + hh*HIMG + ww;
                op[0]      = pr[a][n][0] + pb.x;
                op[HWSZ]   = pr[a][n][1] + pb.y;
                op[2*HWSZ] = pr[a][n][2] + pb.z;
                op[3*HWSZ] = pr[a][n][3] + pb.w;
            }
        }
    }
}

extern "C" void kernel_launch(void* const* d_in, const int* in_sizes, int n_in,
                              void* d_out, int out_size, void* d_ws, size_t ws_size,
                              hipStream_t stream) {
    const float* x      = (const float*)d_in[0];
    const float* qkv_w  = (const float*)d_in[1];
    const float* qkv_b  = (const float*)d_in[2];
    const float* proj_w = (const float*)d_in[3];
    const float* proj_b = (const float*)d_in[4];
    const float* rpb    = (const float*)d_in[5];
    float* out = (float*)d_out;

    // ws bytes: [0,64K) wbias f32 | [64K,160K) hqkv | [160K,192K) hproj
    //           [192K,256K) wbf f32 | [256K,352K) hqkvf | [352K,384K) hprojf
    //           [384K, +75.5M) obuf
    const size_t SETUP = 393216;
    const size_t OSZ   = (size_t)4608 * 16384;

    float* wbias = (float*)d_ws;
    bf16*  hqkv  = (bf16*)((char*)d_ws + 65536);
    bf16*  hproj = (bf16*)((char*)d_ws + 163840);
    float* wbf   = (float*)((char*)d_ws + 196608);
    bf16*  hqkvf = (bf16*)((char*)d_ws + 262144);
    bf16*  hprojf= (bf16*)((char*)d_ws + 360448);
    bf16*  obuf  = (bf16*)((char*)d_ws + SETUP);

    if (ws_size >= SETUP + OSZ) {
        setup_ws<<<640, 256, 0, stream>>>(rpb, qkv_w, proj_w, wbias, hqkv, hproj,
                                          wbf, hqkvf, hprojf);
        qkv_attn<<<4608, 256, 0, stream>>>(x, qkv_b, hqkvf, wbf, obuf);
        proj_rows<<<1536, 512, 0, stream>>>(obuf, hprojf, proj_b, out);
    } else if (ws_size >= SETUP) {
        setup_ws<<<640, 256, 0, stream>>>(rpb, qkv_w, proj_w, wbias, hqkv, hproj,
                                          wbf, hqkvf, hprojf);
        swin_fused<1><<<4608, 64, 0, stream>>>(x, qkv_w, qkv_b, proj_w, proj_b, rpb,
                                               wbias, hqkv, hproj, out);
    } else {
        swin_fused<0><<<4608, 64, 0, stream>>>(x, qkv_w, qkv_b, proj_w, proj_b, rpb,
                                               nullptr, nullptr, nullptr, out);
    }
}